// Round 10
// baseline (179.732 us; speedup 1.0000x reference)
//
#include <hip/hip_runtime.h>
#include <hip/hip_bf16.h>
#include <cstdint>

typedef __attribute__((ext_vector_type(8))) short short8;
typedef __attribute__((ext_vector_type(4))) float f32x4;
typedef __attribute__((ext_vector_type(16))) float f32x16;
typedef unsigned short u16;
typedef unsigned int u32;

__device__ __forceinline__ u16 f2bf(float f) {
    union { float f; u32 u; } v; v.f = f;
    u32 u = v.u;
    u = (u + 0x7fffu + ((u >> 16) & 1u)) >> 16;
    return (u16)u;
}

__device__ __forceinline__ float fexp2(float x) {   // v_exp_f32 = 2^x
    float r;
    asm("v_exp_f32 %0, %1" : "=v"(r) : "v"(x));
    return r;
}

__device__ __forceinline__ u32 pk_bf16(float lo, float hi) {
    u32 r;
    asm("v_cvt_pk_bf16_f32 %0, %1, %2" : "=v"(r) : "v"(lo), "v"(hi));
    return r;
}

__device__ __forceinline__ void pl32swap(u32& a, u32& b) {
#if __has_builtin(__builtin_amdgcn_permlane32_swap)
    auto r = __builtin_amdgcn_permlane32_swap((int)a, (int)b, false, false);
    a = (u32)r[0]; b = (u32)r[1];
#else
    u32 ax = (u32)__shfl_xor((int)a, 32), bx = (u32)__shfl_xor((int)b, 32);
    bool hi = (threadIdx.x & 32) != 0;
    u32 na = hi ? bx : a;
    u32 nb = hi ? b : ax;
    a = na; b = nb;
#endif
}

__device__ __forceinline__ void gload_lds16(const u16* g, u16* l) {
    __builtin_amdgcn_global_load_lds((const __attribute__((address_space(1))) void*)g,
                                     (__attribute__((address_space(3))) void*)l, 16, 0, 0);
}

// C-block rows (crow order) -> one 16-k A/B-frag via cvt_pk + permlane32_swap (T12)
__device__ __forceinline__ short8 make_pa(float p0, float p1, float p2, float p3,
                                          float p4, float p5, float p6, float p7) {
    u32 a1 = pk_bf16(p0, p1), b1 = pk_bf16(p4, p5);
    u32 a2 = pk_bf16(p2, p3), b2 = pk_bf16(p6, p7);
    pl32swap(a1, b1); pl32swap(a2, b2);
    union { u32 w[4]; short8 s; } u;
    u.w[0] = a1; u.w[1] = a2; u.w[2] = b1; u.w[3] = b2;
    return u.s;
}

// ---------- kernel 0: weights prep (blocks 0..799) + mask scan (blocks 800..807) ----------
__global__ void prep_kernel(const float* __restrict__ W_in,
                            const float* __restrict__ W_mh,
                            const float* __restrict__ W_fc,
                            const float* __restrict__ qmask,
                            u16* __restrict__ wcomb, u16* __restrict__ wfc16,
                            u16* __restrict__ win16,
                            u16* __restrict__ pos, u16* __restrict__ inv,
                            int* __restrict__ cnt) {
    if (blockIdx.x >= 800) {                     // per-batch stable compaction scan
        if (threadIdx.x >= 64) return;
        int b = blockIdx.x - 800, t = threadIdx.x;
        int base = b * 2048 + t * 32;
        int c = 0;
#pragma unroll
        for (int i = 0; i < 32; ++i) c += (qmask[base + i] != 0.0f) ? 1 : 0;
        int inc = c;
#pragma unroll
        for (int dd = 1; dd < 64; dd <<= 1) {
            int v = __shfl_up(inc, dd);
            if (t >= dd) inc += v;
        }
        int run = inc - c;
#pragma unroll
        for (int i = 0; i < 32; ++i) {
            bool mk = (qmask[base + i] != 0.0f);
            pos[base + i] = mk ? (u16)run : (u16)0xFFFF;
            if (mk) inv[b * 2048 + run] = (u16)(t * 32 + i);   // compact -> source
            run += mk ? 1 : 0;
        }
        if (t == 63) cnt[b] = inc;
        return;
    }
    int idx = blockIdx.x * 256 + threadIdx.x;
    if (idx < 1024 * 64) {                       // W_comb = W_mh @ W_in
        int f = idx >> 6, i = idx & 63;
        float acc = 0.f;
        for (int e = 0; e < 128; ++e)
            acc += W_mh[f * 128 + e] * W_in[e * 64 + i];
        wcomb[idx] = f2bf(acc);
    }
    int idx2 = idx - 65536;
    if (idx2 >= 0 && idx2 < 128 * 1024)
        wfc16[idx2] = f2bf(W_fc[idx2]);
    int idx3 = idx - 65536 - 131072;
    if (idx3 >= 0 && idx3 < 128 * 64)
        win16[idx3] = f2bf(W_in[idx3]);
}

// ---------- kernel 1: K projection only, compacted rows, LDS-staged 16B stores ----------
__global__ __launch_bounds__(256) void qkv_kernel(
    const float* __restrict__ K,
    const u16* __restrict__ wcomb, const u16* __restrict__ pos,
    u16* __restrict__ kb) {
    __shared__ __align__(16) u16 ot[64 * 264];
    int w = threadIdx.x >> 6, lane = threadIdx.x & 63;
    int g = lane >> 4, c15 = lane & 15;

    int Rrow = blockIdx.x * 64 + w * 16 + c15;
    short8 af[2];
#pragma unroll
    for (int c = 0; c < 2; ++c) {
        const float* p = K + (size_t)Rrow * 64 + 8 * g + 32 * c;
        float4 fa = *(const float4*)(p);
        float4 fb = *(const float4*)(p + 4);
        short8 a;
        a[0] = (short)f2bf(fa.x); a[1] = (short)f2bf(fa.y);
        a[2] = (short)f2bf(fa.z); a[3] = (short)f2bf(fa.w);
        a[4] = (short)f2bf(fb.x); a[5] = (short)f2bf(fb.y);
        a[6] = (short)f2bf(fb.z); a[7] = (short)f2bf(fb.w);
        af[c] = a;
    }
    int colbase = blockIdx.y * 256;
    f32x4 acc[16];
#pragma unroll
    for (int i = 0; i < 16; ++i) acc[i] = {0.f, 0.f, 0.f, 0.f};
#pragma unroll
    for (int cb = 0; cb < 16; ++cb) {
        int col = colbase + cb * 16 + c15;
#pragma unroll
        for (int c = 0; c < 2; ++c) {
            short8 bfr = *(const short8*)(wcomb + (size_t)col * 64 + 8 * g + 32 * c);
            acc[cb] = __builtin_amdgcn_mfma_f32_16x16x32_bf16(af[c], bfr, acc[cb], 0, 0, 0);
        }
    }
    int r0 = w * 16 + 4 * g;
#pragma unroll
    for (int cb = 0; cb < 16; ++cb)
#pragma unroll
        for (int r = 0; r < 4; ++r)
            ot[(r0 + r) * 264 + cb * 16 + c15] = f2bf(acc[cb][r]);
    __syncthreads();
#pragma unroll
    for (int it = 0; it < 8; ++it) {
        int chunk = threadIdx.x + it * 256;
        int row = chunk >> 5, cc = chunk & 31;
        int R = blockIdx.x * 64 + row;
        u16 p = pos[R];
        if (p != 0xFFFF) {
            int b = R >> 11;
            int col0 = colbase + cc * 8;
            int h = col0 >> 7, d = col0 & 127;
            *(uint4*)(kb + ((size_t)(b * 8 + h) * 2048 + p) * 128 + d) =
                *(const uint4*)(ot + row * 264 + cc * 8);
        }
    }
}

// ---------- kernel 2: gather raw V rows (inv map) + project + emit chunk-major vT ----------
__global__ __launch_bounds__(256) void vtrans_kernel(
    const float* __restrict__ V, const u16* __restrict__ wcomb,
    const u16* __restrict__ inv, const int* __restrict__ cnt,
    u16* __restrict__ vT) {
    int t = blockIdx.x, bh = blockIdx.y, b = bh >> 3, h = bh & 7;
    int L = cnt[b];
    if (t * 64 >= L) return;
    __shared__ __align__(16) u16 ot[64 * 136];
    __shared__ __align__(16) u32 tl[128 * 32];

    int w = threadIdx.x >> 6, lane = threadIdx.x & 63;
    int g = lane >> 4, c15 = lane & 15;

    // gather + bf16-convert the A fragment (compacted row = t*64 + w*16 + c15)
    int lr = w * 16 + c15;
    bool okr = (t * 64 + lr < L);
    int src = okr ? (int)inv[b * 2048 + t * 64 + lr] : 0;
    short8 af[2] = {};
    if (okr) {
        const float* p0 = V + ((size_t)b * 2048 + src) * 64;
#pragma unroll
        for (int c = 0; c < 2; ++c) {
            float4 fa = *(const float4*)(p0 + 8 * g + 32 * c);
            float4 fb = *(const float4*)(p0 + 8 * g + 32 * c + 4);
            short8 a;
            a[0] = (short)f2bf(fa.x); a[1] = (short)f2bf(fa.y);
            a[2] = (short)f2bf(fa.z); a[3] = (short)f2bf(fa.w);
            a[4] = (short)f2bf(fb.x); a[5] = (short)f2bf(fb.y);
            a[6] = (short)f2bf(fb.z); a[7] = (short)f2bf(fb.w);
            af[c] = a;
        }
    }
    // project to head h's 128 columns
    f32x4 acc[8];
#pragma unroll
    for (int i = 0; i < 8; ++i) acc[i] = {0.f, 0.f, 0.f, 0.f};
#pragma unroll
    for (int cb = 0; cb < 8; ++cb) {
        int col = h * 128 + cb * 16 + c15;
#pragma unroll
        for (int c = 0; c < 2; ++c) {
            short8 bfr = *(const short8*)(wcomb + (size_t)col * 64 + 8 * g + 32 * c);
            acc[cb] = __builtin_amdgcn_mfma_f32_16x16x32_bf16(af[c], bfr, acc[cb], 0, 0, 0);
        }
    }
    int rr0 = w * 16 + 4 * g;
#pragma unroll
    for (int cb = 0; cb < 8; ++cb)
#pragma unroll
        for (int r = 0; r < 4; ++r)
            ot[(rr0 + r) * 136 + cb * 16 + c15] = f2bf(acc[cb][r]);
    __syncthreads();

    // row-pair interleave (from ot) -> XOR-swizzled tl
#pragma unroll
    for (int task = 0; task < 2; ++task) {
        int id = threadIdx.x + task * 256;       // 512 tasks: s-pair i x d-chunk c
        int i = id >> 4, c = id & 15;
        uint4 A  = *(const uint4*)(ot + (2 * i) * 136 + c * 8);
        uint4 Bv = *(const uint4*)(ot + (2 * i + 1) * 136 + c * 8);
        const u32* aw = (const u32*)&A;
        const u32* bw = (const u32*)&Bv;
#pragma unroll
        for (int j = 0; j < 4; ++j) {
            u32 lo  = (aw[j] & 0xFFFFu) | (bw[j] << 16);       // d=8c+2j
            u32 hi2 = (aw[j] >> 16) | (bw[j] & 0xFFFF0000u);   // d=8c+2j+1
            int d0 = 8 * c + 2 * j, d1 = d0 + 1;
            int h0 = ((d0 & 7) ^ ((d0 >> 3) & 7)) << 2;
            int h1 = ((d1 & 7) ^ ((d1 >> 3) & 7)) << 2;
            tl[d0 * 32 + (i ^ h0)] = lo;
            tl[d1 * 32 + (i ^ h1)] = hi2;
        }
    }
    __syncthreads();
    int d = threadIdx.x >> 1, half = threadIdx.x & 1;
    int hd = (d & 7) ^ ((d >> 3) & 7);
#pragma unroll
    for (int jc = 0; jc < 4; ++jc) {
        int chunk = (half * 4 + jc) ^ hd;
        int kcg = t * 8 + half * 4 + jc;         // global 8-key chunk index
        *(uint4*)(vT + (((size_t)bh * 256 + kcg) * 128 + d) * 8) =
            *(const uint4*)(&tl[d * 32 + chunk * 4]);
    }
}

// ---------- kernel 3: flash attn (r5 structure) + fused W_fc GEMM + residual + LN ----------
__global__ __launch_bounds__(512, 2) void attn_kernel(
    const float* __restrict__ Qin, const u16* __restrict__ wcomb,
    const u16* __restrict__ kbuf, const u16* __restrict__ vTc,
    const int* __restrict__ cnt,
    const u16* __restrict__ wfc16, const u16* __restrict__ win16,
    const float* __restrict__ ln_g, const float* __restrict__ ln_b,
    float* __restrict__ out) {
    __shared__ __align__(16) u16 smem[33792];    // kt[2][8192]|vt[2][8192]; epi overlay padded
    __shared__ float2 pls[32][4];                // LN partials: [row][colgroup] (sum, sumsq)

    const int w = threadIdx.x >> 6, lane = threadIdx.x & 63;
    const int hi = lane >> 5, l31 = lane & 31;
    const int g = lane >> 4, c15 = lane & 15;
    const int bh = blockIdx.x, qt = blockIdx.y;  // XCD = bh%8: all qt of a bh share L2
    const int b = bh >> 3, h = bh & 7;
    const int L = cnt[b];
    const int nt = (L + 63) >> 6;

    const u16* kbbh = kbuf + (size_t)bh * 2048 * 128;
    const u16* vTbh = vTc + (size_t)bh * 262144; // 256 kcg * 128 d * 8

    u16* ktb0 = smem;                            // [2][8192]
    u16* vtb0 = smem + 16384;                    // [2][8192] chunk-major: (kcg*128+d)*8

    auto stage = [&](int buf, int tt) {
#pragma unroll
        for (int c = 0; c < 2; ++c) {
            int rl = (c * 8 + w) * 4 + (lane >> 4);     // K: 4 rows per wave-call
            int ck = (lane & 15) ^ (rl & 7);
            gload_lds16(kbbh + ((size_t)(tt * 64 + rl)) * 128 + ck * 8,
                        ktb0 + buf * 8192 + (c * 8 + w) * 512);
            int ci = c * 512 + w * 64 + lane;           // V: pure linear block copy
            gload_lds16(vTbh + ((size_t)tt * 1024 + ci) * 8,
                        vtb0 + buf * 8192 + (c * 512 + w * 64) * 8);
        }
    };

    stage(0, 0);                                 // DMA overlaps q-projection below

    // ---- fused q-projection, scaled by log2(e)/sqrt(128) (softmax in log2 domain) ----
    const float invT2 = 0.12751743f;             // log2(e)/sqrt(128)
    const int q0 = qt * 256 + w * 32;
    const float* qrow = Qin + ((size_t)b * 2048 + q0 + l31) * 64;
    short8 bq[4];
#pragma unroll
    for (int s = 0; s < 4; ++s) {
        const float* p = qrow + s * 16 + hi * 8;
        float4 fa = *(const float4*)(p);
        float4 fb = *(const float4*)(p + 4);
        short8 a;
        a[0] = (short)f2bf(fa.x); a[1] = (short)f2bf(fa.y);
        a[2] = (short)f2bf(fa.z); a[3] = (short)f2bf(fa.w);
        a[4] = (short)f2bf(fb.x); a[5] = (short)f2bf(fb.y);
        a[6] = (short)f2bf(fb.z); a[7] = (short)f2bf(fb.w);
        bq[s] = a;
    }
    short8 qf[8];
#pragma unroll
    for (int dblk = 0; dblk < 4; ++dblk) {
        f32x16 c2;
#pragma unroll
        for (int r = 0; r < 16; ++r) c2[r] = 0.f;
        const u16* wrow = wcomb + (size_t)(h * 128 + dblk * 32 + l31) * 64 + hi * 8;
#pragma unroll
        for (int s = 0; s < 4; ++s) {
            short8 wa = *(const short8*)(wrow + s * 16);
            c2 = __builtin_amdgcn_mfma_f32_32x32x16_bf16(wa, bq[s], c2, 0, 0, 0);
        }
        qf[2 * dblk] = make_pa(c2[0] * invT2, c2[1] * invT2, c2[2] * invT2, c2[3] * invT2,
                               c2[4] * invT2, c2[5] * invT2, c2[6] * invT2, c2[7] * invT2);
        qf[2 * dblk + 1] = make_pa(c2[8] * invT2, c2[9] * invT2, c2[10] * invT2, c2[11] * invT2,
                                   c2[12] * invT2, c2[13] * invT2, c2[14] * invT2, c2[15] * invT2);
    }

    f32x16 o[4];
#pragma unroll
    for (int i = 0; i < 4; ++i)
#pragma unroll
        for (int r = 0; r < 16; ++r) o[i][r] = 0.f;
    float m = -1e30f, lsum = 0.f;

    int cur = 0;
    __syncthreads();

    for (int t = 0; t < nt; ++t) {
        if (t + 1 < nt) stage(cur ^ 1, t + 1);
        const u16* ktb = ktb0 + cur * 8192;
        const u16* vtb = vtb0 + cur * 8192;

        // S^T = K . Q^T (log2 domain)
        f32x16 st0, st1;
#pragma unroll
        for (int r = 0; r < 16; ++r) { st0[r] = 0.f; st1[r] = 0.f; }
        int k0 = l31, k1 = 32 + l31;
#pragma unroll
        for (int ds = 0; ds < 8; ++ds) {
            int sw = ((ds * 2 + hi) ^ (l31 & 7)) << 3;
            short8 kf0 = *(const short8*)(ktb + (k0 << 7) + sw);
            short8 kf1 = *(const short8*)(ktb + (k1 << 7) + sw);
            st0 = __builtin_amdgcn_mfma_f32_32x32x16_bf16(kf0, qf[ds], st0, 0, 0, 0);
            st1 = __builtin_amdgcn_mfma_f32_32x32x16_bf16(kf1, qf[ds], st1, 0, 0, 0);
        }
        if (t == nt - 1) {                      // tail: replace (kills garbage NaN/Inf)
#pragma unroll
            for (int r = 0; r < 16; ++r) {
                int kl = (r & 3) + 8 * (r >> 2) + 4 * hi;
                st0[r] = (t * 64 + kl < L) ? st0[r] : -1e30f;
                st1[r] = (t * 64 + 32 + kl < L) ? st1[r] : -1e30f;
            }
        }
        float mx = st0[0];
#pragma unroll
        for (int r = 1; r < 16; ++r) mx = fmaxf(mx, st0[r]);
#pragma unroll
        for (int r = 0; r < 16; ++r) mx = fmaxf(mx, st1[r]);
        mx = fmaxf(mx, __shfl_xor(mx, 32));
        if (__any(mx - m > 11.0f)) {            // defer-max (log2 units)
            float mn = fmaxf(m, mx);
            float corr = fexp2(m - mn);
            m = mn;
            lsum *= corr;
#pragma unroll
            for (int r = 0; r < 16; ++r) {
                float cc = __shfl(corr, (r & 3) + 8 * (r >> 2) + 4 * hi);
                o[0][r] *= cc; o[1][r] *= cc; o[2][r] *= cc; o[3][r] *= cc;
            }
        }
        float p0a[16], p1a[16];
#pragma unroll
        for (int r = 0; r < 16; ++r) { p0a[r] = fexp2(st0[r] - m); p1a[r] = fexp2(st1[r] - m); }
        float s0 = 0.f, s1 = 0.f, s2 = 0.f, s3 = 0.f;
#pragma unroll
        for (int r = 0; r < 16; r += 4) {
            s0 += p0a[r]; s1 += p0a[r + 1]; s2 += p0a[r + 2]; s3 += p0a[r + 3];
            s0 += p1a[r]; s1 += p1a[r + 1]; s2 += p1a[r + 2]; s3 += p1a[r + 3];
        }
        float tot = (s0 + s1) + (s2 + s3);
        tot += __shfl_xor(tot, 32);
        lsum += tot;
        short8 pa0 = make_pa(p0a[0], p0a[1], p0a[2], p0a[3], p0a[4], p0a[5], p0a[6], p0a[7]);
        short8 pa1 = make_pa(p0a[8], p0a[9], p0a[10], p0a[11], p0a[12], p0a[13], p0a[14], p0a[15]);
        short8 pa2 = make_pa(p1a[0], p1a[1], p1a[2], p1a[3], p1a[4], p1a[5], p1a[6], p1a[7]);
        short8 pa3 = make_pa(p1a[8], p1a[9], p1a[10], p1a[11], p1a[12], p1a[13], p1a[14], p1a[15]);
        // O += P @ V ; V chunk-major (linear, conflict-free)
#pragma unroll
        for (int dblk = 0; dblk < 4; ++dblk) {
#pragma unroll
            for (int ks = 0; ks < 4; ++ks) {
                short8 vf = *(const short8*)(vtb +
                    ((((ks * 2 + hi) << 7) + (dblk << 5) + l31) << 3));
                short8 pa = (ks == 0) ? pa0 : (ks == 1) ? pa1 : (ks == 2) ? pa2 : pa3;
                o[dblk] = __builtin_amdgcn_mfma_f32_32x32x16_bf16(pa, vf, o[dblk], 0, 0, 0);
            }
        }
        __syncthreads();
        cur ^= 1;
    }

    // ---- fused epilogue: stage 32x1024 attn-out into LDS, padded chunk-major ----
    // epi[cw*264 + row*8 + slot]: cw stride 528B == 132 dwords -> +4 bank shift per cw
    u16* epi = smem;
    float invl = 1.0f / lsum;
#pragma unroll
    for (int r = 0; r < 16; ++r) {
        int kl = (r & 3) + 8 * (r >> 2) + 4 * hi;
        float iv = __shfl(invl, kl);
        int row_local = w * 4 + (kl >> 3);
        int cb2 = (kl & 7) * 16 + (l31 >> 3);
#pragma unroll
        for (int dblk = 0; dblk < 4; ++dblk) {
            int cw = cb2 + dblk * 4;
            epi[cw * 264 + row_local * 8 + (l31 & 7)] = f2bf(o[dblk][r] * iv);
        }
    }
    __syncthreads();

    // ---- W_fc GEMM (K=1024 from epi) + residual Q@W_in (K=64), parity-split accs ----
    const int rg = w >> 2, cg = w & 3;           // 2 rowgroups x 4 colgroups
    const int srow0 = h * 256 + qt * 32;
    const int row16 = rg * 16 + c15;
    f32x4 acA[2], acB[2];
    acA[0] = {0.f, 0.f, 0.f, 0.f}; acA[1] = {0.f, 0.f, 0.f, 0.f};
    acB[0] = {0.f, 0.f, 0.f, 0.f}; acB[1] = {0.f, 0.f, 0.f, 0.f};
    {   // residual -> acA
        const float* p0 = Qin + ((size_t)b * 2048 + srow0 + row16) * 64;
        short8 af2[2];
#pragma unroll
        for (int c = 0; c < 2; ++c) {
            float4 fa = *(const float4*)(p0 + 8 * g + 32 * c);
            float4 fb = *(const float4*)(p0 + 8 * g + 32 * c + 4);
            short8 a;
            a[0] = (short)f2bf(fa.x); a[1] = (short)f2bf(fa.y);
            a[2] = (short)f2bf(fa.z); a[3] = (short)f2bf(fa.w);
            a[4] = (short)f2bf(fb.x); a[5] = (short)f2bf(fb.y);
            a[6] = (short)f2bf(fb.z); a[7] = (short)f2bf(fb.w);
            af2[c] = a;
        }
#pragma unroll
        for (int eb = 0; eb < 2; ++eb)
#pragma unroll
            for (int c = 0; c < 2; ++c) {
                short8 bfr = *(const short8*)(win16 +
                    (size_t)(cg * 32 + eb * 16 + c15) * 64 + 8 * g + 32 * c);
                acA[eb] = __builtin_amdgcn_mfma_f32_16x16x32_bf16(af2[c], bfr, acA[eb], 0, 0, 0);
            }
    }
#pragma unroll
    for (int kc2 = 0; kc2 < 16; ++kc2) {
        int kcE = 2 * kc2, kcO = 2 * kc2 + 1;
        short8 afE = *(const short8*)(epi + (kcE * 4 + g) * 264 + row16 * 8);
        short8 afO = *(const short8*)(epi + (kcO * 4 + g) * 264 + row16 * 8);
#pragma unroll
        for (int eb = 0; eb < 2; ++eb) {
            short8 bfE = *(const short8*)(wfc16 +
                (size_t)(cg * 32 + eb * 16 + c15) * 1024 + kcE * 32 + 8 * g);
            short8 bfO = *(const short8*)(wfc16 +
                (size_t)(cg * 32 + eb * 16 + c15) * 1024 + kcO * 32 + 8 * g);
            acA[eb] = __builtin_amdgcn_mfma_f32_16x16x32_bf16(afE, bfE, acA[eb], 0, 0, 0);
            acB[eb] = __builtin_amdgcn_mfma_f32_16x16x32_bf16(afO, bfO, acB[eb], 0, 0, 0);
        }
    }
    f32x4 acc2[2];
#pragma unroll
    for (int eb = 0; eb < 2; ++eb)
#pragma unroll
        for (int r = 0; r < 4; ++r)
            acc2[eb][r] = acA[eb][r] + acB[eb][r];
    // ---- LN partials across colgroups ----
#pragma unroll
    for (int r = 0; r < 4; ++r) {
        float s = acc2[0][r] + acc2[1][r];
        float q2 = acc2[0][r] * acc2[0][r] + acc2[1][r] * acc2[1][r];
#pragma unroll
        for (int dd = 1; dd < 16; dd <<= 1) {
            s += __shfl_xor(s, dd);
            q2 += __shfl_xor(q2, dd);
        }
        if (c15 == 0) pls[rg * 16 + 4 * g + r][cg] = make_float2(s, q2);
    }
    __syncthreads();
    float gg0 = ln_g[cg * 32 + c15],      bb0 = ln_b[cg * 32 + c15];
    float gg1 = ln_g[cg * 32 + 16 + c15], bb1 = ln_b[cg * 32 + 16 + c15];
#pragma unroll
    for (int r = 0; r < 4; ++r) {
        int row = rg * 16 + 4 * g + r;
        float2 pa = pls[row][0], pb = pls[row][1], pc = pls[row][2], pd = pls[row][3];
        float mean = (pa.x + pb.x + pc.x + pd.x) * (1.0f / 128.0f);
        float var  = (pa.y + pb.y + pc.y + pd.y) * (1.0f / 128.0f) - mean * mean;
        float rstd = rsqrtf(var + 1e-6f);
        size_t ob = ((size_t)b * 2048 + srow0 + row) * 128;
        out[ob + cg * 32 + c15]      = (acc2[0][r] - mean) * rstd * gg0 + bb0;
        out[ob + cg * 32 + 16 + c15] = (acc2[1][r] - mean) * rstd * gg1 + bb1;
    }
}

// ---------- launcher ----------
extern "C" void kernel_launch(void* const* d_in, const int* in_sizes, int n_in,
                              void* d_out, int out_size, void* d_ws, size_t ws_size,
                              hipStream_t stream) {
    const float* Q     = (const float*)d_in[0];
    const float* K     = (const float*)d_in[1];
    const float* V     = (const float*)d_in[2];
    const float* QMask = (const float*)d_in[3];
    const float* W_in  = (const float*)d_in[4];
    const float* W_mh  = (const float*)d_in[5];
    const float* W_fc  = (const float*)d_in[6];
    const float* ln_g  = (const float*)d_in[7];
    const float* ln_b  = (const float*)d_in[8];
    float* out = (float*)d_out;

    char* ws = (char*)d_ws;
    u16*   wcomb = (u16*)(ws);                   // 131072 B
    u16*   wfc16 = (u16*)(ws + 131072);          // 262144 B
    u16*   kb    = (u16*)(ws + 42336256);        // compacted K rows [B*H,S,128]
    u16*   vT    = (u16*)(ws + 75890688);        // chunk-major [B*H][256 kcg][128 d][8]
    u16*   pos   = (u16*)(ws + 142999552);       // [B,S] compact position or 0xFFFF
    int*   cnt   = (int*)(ws + 143032320);       // [B] unmasked counts
    u16*   win16 = (u16*)(ws + 143036416);       // W_in bf16 [128][64]
    u16*   inv   = (u16*)(ws + 143052800);       // [B,S] compact -> source row

    hipLaunchKernelGGL(prep_kernel, dim3(808), dim3(256), 0, stream,
                       W_in, W_mh, W_fc, QMask, wcomb, wfc16, win16, pos, inv, cnt);
    hipLaunchKernelGGL(qkv_kernel, dim3(256, 4), dim3(256), 0, stream,
                       K, wcomb, pos, kb);
    hipLaunchKernelGGL(vtrans_kernel, dim3(32, 64), dim3(256), 0, stream,
                       V, wcomb, inv, cnt, vT);
    hipLaunchKernelGGL(attn_kernel, dim3(64, 8), dim3(512), 0, stream,
                       Q, wcomb, kb, vT, cnt, wfc16, win16, ln_g, ln_b, out);
}

// Round 11
// 176.509 us; speedup vs baseline: 1.0183x; 1.0183x over previous
//
#include <hip/hip_runtime.h>
#include <hip/hip_bf16.h>
#include <cstdint>

typedef __attribute__((ext_vector_type(8))) short short8;
typedef __attribute__((ext_vector_type(4))) float f32x4;
typedef __attribute__((ext_vector_type(16))) float f32x16;
typedef unsigned short u16;
typedef unsigned int u32;

__device__ __forceinline__ u16 f2bf(float f) {
    union { float f; u32 u; } v; v.f = f;
    u32 u = v.u;
    u = (u + 0x7fffu + ((u >> 16) & 1u)) >> 16;
    return (u16)u;
}

__device__ __forceinline__ float fexp2(float x) {   // v_exp_f32 = 2^x
    float r;
    asm("v_exp_f32 %0, %1" : "=v"(r) : "v"(x));
    return r;
}

__device__ __forceinline__ u32 pk_bf16(float lo, float hi) {
    u32 r;
    asm("v_cvt_pk_bf16_f32 %0, %1, %2" : "=v"(r) : "v"(lo), "v"(hi));
    return r;
}

__device__ __forceinline__ void pl32swap(u32& a, u32& b) {
#if __has_builtin(__builtin_amdgcn_permlane32_swap)
    auto r = __builtin_amdgcn_permlane32_swap((int)a, (int)b, false, false);
    a = (u32)r[0]; b = (u32)r[1];
#else
    u32 ax = (u32)__shfl_xor((int)a, 32), bx = (u32)__shfl_xor((int)b, 32);
    bool hi = (threadIdx.x & 32) != 0;
    u32 na = hi ? bx : a;
    u32 nb = hi ? b : ax;
    a = na; b = nb;
#endif
}

__device__ __forceinline__ void gload_lds16(const u16* g, u16* l) {
    __builtin_amdgcn_global_load_lds((const __attribute__((address_space(1))) void*)g,
                                     (__attribute__((address_space(3))) void*)l, 16, 0, 0);
}

// C-block rows (crow order) -> one 16-k A/B-frag via cvt_pk + permlane32_swap (T12)
__device__ __forceinline__ short8 make_pa(float p0, float p1, float p2, float p3,
                                          float p4, float p5, float p6, float p7) {
    u32 a1 = pk_bf16(p0, p1), b1 = pk_bf16(p4, p5);
    u32 a2 = pk_bf16(p2, p3), b2 = pk_bf16(p6, p7);
    pl32swap(a1, b1); pl32swap(a2, b2);
    union { u32 w[4]; short8 s; } u;
    u.w[0] = a1; u.w[1] = a2; u.w[2] = b1; u.w[3] = b2;
    return u.s;
}

// ---------- kernel 0: weights prep (blocks 0..799) + mask scan (blocks 800..807) ----------
__global__ void prep_kernel(const float* __restrict__ W_in,
                            const float* __restrict__ W_mh,
                            const float* __restrict__ W_fc,
                            const float* __restrict__ qmask,
                            u16* __restrict__ wcomb, u16* __restrict__ wfc16,
                            u16* __restrict__ win16,
                            u16* __restrict__ pos, int* __restrict__ cnt) {
    if (blockIdx.x >= 800) {                     // per-batch stable compaction scan
        if (threadIdx.x >= 64) return;
        int b = blockIdx.x - 800, t = threadIdx.x;
        int base = b * 2048 + t * 32;
        int c = 0;
#pragma unroll
        for (int i = 0; i < 32; ++i) c += (qmask[base + i] != 0.0f) ? 1 : 0;
        int inc = c;
#pragma unroll
        for (int dd = 1; dd < 64; dd <<= 1) {
            int v = __shfl_up(inc, dd);
            if (t >= dd) inc += v;
        }
        int run = inc - c;
#pragma unroll
        for (int i = 0; i < 32; ++i) {
            bool mk = (qmask[base + i] != 0.0f);
            pos[base + i] = mk ? (u16)run : (u16)0xFFFF;
            run += mk ? 1 : 0;
        }
        if (t == 63) cnt[b] = inc;
        return;
    }
    int idx = blockIdx.x * 256 + threadIdx.x;
    if (idx < 1024 * 64) {                       // W_comb = W_mh @ W_in
        int f = idx >> 6, i = idx & 63;
        float acc = 0.f;
        for (int e = 0; e < 128; ++e)
            acc += W_mh[f * 128 + e] * W_in[e * 64 + i];
        wcomb[idx] = f2bf(acc);
    }
    int idx2 = idx - 65536;
    if (idx2 >= 0 && idx2 < 128 * 1024)
        wfc16[idx2] = f2bf(W_fc[idx2]);
    int idx3 = idx - 65536 - 131072;
    if (idx3 >= 0 && idx3 < 128 * 64)
        win16[idx3] = f2bf(W_in[idx3]);
}

// ---------- kernel 1: k/v projections, compacted rows, LDS-staged 16B stores ----------
__global__ __launch_bounds__(256) void qkv_kernel(
    const float* __restrict__ K, const float* __restrict__ V,
    const u16* __restrict__ wcomb, const u16* __restrict__ pos,
    u16* __restrict__ kb, u16* __restrict__ vrow) {
    __shared__ __align__(16) u16 ot[64 * 264];
    int w = threadIdx.x >> 6, lane = threadIdx.x & 63;
    int g = lane >> 4, c15 = lane & 15;
    const float* X = blockIdx.z == 0 ? K : V;

    int Rrow = blockIdx.x * 64 + w * 16 + c15;
    short8 af[2];
#pragma unroll
    for (int c = 0; c < 2; ++c) {
        const float* p = X + (size_t)Rrow * 64 + 8 * g + 32 * c;
        float4 fa = *(const float4*)(p);
        float4 fb = *(const float4*)(p + 4);
        short8 a;
        a[0] = (short)f2bf(fa.x); a[1] = (short)f2bf(fa.y);
        a[2] = (short)f2bf(fa.z); a[3] = (short)f2bf(fa.w);
        a[4] = (short)f2bf(fb.x); a[5] = (short)f2bf(fb.y);
        a[6] = (short)f2bf(fb.z); a[7] = (short)f2bf(fb.w);
        af[c] = a;
    }
    int colbase = blockIdx.y * 256;
    f32x4 acc[16];
#pragma unroll
    for (int i = 0; i < 16; ++i) acc[i] = {0.f, 0.f, 0.f, 0.f};
#pragma unroll
    for (int cb = 0; cb < 16; ++cb) {
        int col = colbase + cb * 16 + c15;
#pragma unroll
        for (int c = 0; c < 2; ++c) {
            short8 bfr = *(const short8*)(wcomb + (size_t)col * 64 + 8 * g + 32 * c);
            acc[cb] = __builtin_amdgcn_mfma_f32_16x16x32_bf16(af[c], bfr, acc[cb], 0, 0, 0);
        }
    }
    int r0 = w * 16 + 4 * g;
#pragma unroll
    for (int cb = 0; cb < 16; ++cb)
#pragma unroll
        for (int r = 0; r < 4; ++r)
            ot[(r0 + r) * 264 + cb * 16 + c15] = f2bf(acc[cb][r]);
    __syncthreads();
    u16* dstbuf = blockIdx.z == 0 ? kb : vrow;
#pragma unroll
    for (int it = 0; it < 8; ++it) {
        int chunk = threadIdx.x + it * 256;
        int row = chunk >> 5, cc = chunk & 31;
        int R = blockIdx.x * 64 + row;
        u16 p = pos[R];
        if (p != 0xFFFF) {
            int b = R >> 11;
            int col0 = colbase + cc * 8;
            int h = col0 >> 7, d = col0 & 127;
            *(uint4*)(dstbuf + ((size_t)(b * 8 + h) * 2048 + p) * 128 + d) =
                *(const uint4*)(ot + row * 264 + cc * 8);
        }
    }
}

// ---------- kernel 2: transpose compacted V rows -> chunk-major vT[bh][kcg][128][8] ----------
__global__ __launch_bounds__(256) void vtrans_kernel(
    const u16* __restrict__ vrow, const int* __restrict__ cnt,
    u16* __restrict__ vT) {
    int t = blockIdx.x, bh = blockIdx.y, b = bh >> 3;
    int L = cnt[b];
    if (t * 64 >= L) return;
    __shared__ __align__(16) u32 tl[128 * 32];   // [d][32 s-pairs], chunk-XOR swizzled
    const u16* src = vrow + ((size_t)bh * 2048 + t * 64) * 128;
#pragma unroll
    for (int task = 0; task < 2; ++task) {
        int id = threadIdx.x + task * 256;       // 512 tasks: s-pair i x d-chunk c
        int i = id >> 4, c = id & 15;
        int r0 = 2 * i, r1 = 2 * i + 1;
        uint4 A = {0, 0, 0, 0}, Bv = {0, 0, 0, 0};
        if (t * 64 + r0 < L) A  = *(const uint4*)(src + (size_t)r0 * 128 + c * 8);
        if (t * 64 + r1 < L) Bv = *(const uint4*)(src + (size_t)r1 * 128 + c * 8);
        const u32* aw = (const u32*)&A;
        const u32* bw = (const u32*)&Bv;
#pragma unroll
        for (int j = 0; j < 4; ++j) {
            u32 lo  = (aw[j] & 0xFFFFu) | (bw[j] << 16);       // d=8c+2j,  rows (r0,r1)
            u32 hi2 = (aw[j] >> 16) | (bw[j] & 0xFFFF0000u);   // d=8c+2j+1
            int d0 = 8 * c + 2 * j, d1 = d0 + 1;
            int h0 = ((d0 & 7) ^ ((d0 >> 3) & 7)) << 2;
            int h1 = ((d1 & 7) ^ ((d1 >> 3) & 7)) << 2;
            tl[d0 * 32 + (i ^ h0)] = lo;
            tl[d1 * 32 + (i ^ h1)] = hi2;
        }
    }
    __syncthreads();
    int d = threadIdx.x >> 1, half = threadIdx.x & 1;
    int hd = (d & 7) ^ ((d >> 3) & 7);
#pragma unroll
    for (int jc = 0; jc < 4; ++jc) {
        int chunk = (half * 4 + jc) ^ hd;
        int kcg = t * 8 + half * 4 + jc;         // global 8-key chunk index
        *(uint4*)(vT + (((size_t)bh * 256 + kcg) * 128 + d) * 8) =
            *(const uint4*)(&tl[d * 32 + chunk * 4]);
    }
}

// ---------- kernel 3: flash attn (r5 structure) + fused W_fc GEMM + residual + LN ----------
__global__ __launch_bounds__(512, 2) void attn_kernel(
    const float* __restrict__ Qin, const u16* __restrict__ wcomb,
    const u16* __restrict__ kbuf, const u16* __restrict__ vTc,
    const int* __restrict__ cnt,
    const u16* __restrict__ wfc16, const u16* __restrict__ win16,
    const float* __restrict__ ln_g, const float* __restrict__ ln_b,
    float* __restrict__ out) {
    __shared__ __align__(16) u16 smem[32768];    // kt[2][8192] | vt[2][8192]; epi overlay
    __shared__ float2 pls[32][4];                // LN partials: [row][colgroup] (sum, sumsq)

    const int w = threadIdx.x >> 6, lane = threadIdx.x & 63;
    const int hi = lane >> 5, l31 = lane & 31;
    const int g = lane >> 4, c15 = lane & 15;
    const int bh = blockIdx.x, qt = blockIdx.y;  // XCD = bh%8: all qt of a bh share L2
    const int b = bh >> 3, h = bh & 7;
    const int L = cnt[b];
    const int nt = (L + 63) >> 6;

    const u16* kbbh = kbuf + (size_t)bh * 2048 * 128;
    const u16* vTbh = vTc + (size_t)bh * 262144; // 256 kcg * 128 d * 8

    u16* ktb0 = smem;                            // [2][8192]
    u16* vtb0 = smem + 16384;                    // [2][8192] chunk-major: (kcg*128+d)*8

    auto stage = [&](int buf, int tt) {
#pragma unroll
        for (int c = 0; c < 2; ++c) {
            int rl = (c * 8 + w) * 4 + (lane >> 4);     // K: 4 rows per wave-call
            int ck = (lane & 15) ^ (rl & 7);
            gload_lds16(kbbh + ((size_t)(tt * 64 + rl)) * 128 + ck * 8,
                        ktb0 + buf * 8192 + (c * 8 + w) * 512);
            int ci = c * 512 + w * 64 + lane;           // V: pure linear block copy
            gload_lds16(vTbh + ((size_t)tt * 1024 + ci) * 8,
                        vtb0 + buf * 8192 + (c * 512 + w * 64) * 8);
        }
    };

    stage(0, 0);                                 // DMA overlaps q-projection below

    // ---- fused q-projection, scaled by log2(e)/sqrt(128) (softmax in log2 domain) ----
    const float invT2 = 0.12751743f;             // log2(e)/sqrt(128)
    const int q0 = qt * 256 + w * 32;
    const float* qrow = Qin + ((size_t)b * 2048 + q0 + l31) * 64;
    short8 bq[4];
#pragma unroll
    for (int s = 0; s < 4; ++s) {
        const float* p = qrow + s * 16 + hi * 8;
        float4 fa = *(const float4*)(p);
        float4 fb = *(const float4*)(p + 4);
        short8 a;
        a[0] = (short)f2bf(fa.x); a[1] = (short)f2bf(fa.y);
        a[2] = (short)f2bf(fa.z); a[3] = (short)f2bf(fa.w);
        a[4] = (short)f2bf(fb.x); a[5] = (short)f2bf(fb.y);
        a[6] = (short)f2bf(fb.z); a[7] = (short)f2bf(fb.w);
        bq[s] = a;
    }
    short8 qf[8];
#pragma unroll
    for (int dblk = 0; dblk < 4; ++dblk) {
        f32x16 c2;
#pragma unroll
        for (int r = 0; r < 16; ++r) c2[r] = 0.f;
        const u16* wrow = wcomb + (size_t)(h * 128 + dblk * 32 + l31) * 64 + hi * 8;
#pragma unroll
        for (int s = 0; s < 4; ++s) {
            short8 wa = *(const short8*)(wrow + s * 16);
            c2 = __builtin_amdgcn_mfma_f32_32x32x16_bf16(wa, bq[s], c2, 0, 0, 0);
        }
        qf[2 * dblk] = make_pa(c2[0] * invT2, c2[1] * invT2, c2[2] * invT2, c2[3] * invT2,
                               c2[4] * invT2, c2[5] * invT2, c2[6] * invT2, c2[7] * invT2);
        qf[2 * dblk + 1] = make_pa(c2[8] * invT2, c2[9] * invT2, c2[10] * invT2, c2[11] * invT2,
                                   c2[12] * invT2, c2[13] * invT2, c2[14] * invT2, c2[15] * invT2);
    }

    f32x16 o[4];
#pragma unroll
    for (int i = 0; i < 4; ++i)
#pragma unroll
        for (int r = 0; r < 16; ++r) o[i][r] = 0.f;
    float m = -1e30f, lsum = 0.f;

    int cur = 0;
    __syncthreads();

    for (int t = 0; t < nt; ++t) {
        if (t + 1 < nt) stage(cur ^ 1, t + 1);
        const u16* ktb = ktb0 + cur * 8192;
        const u16* vtb = vtb0 + cur * 8192;

        // S^T = K . Q^T (log2 domain)
        f32x16 st0, st1;
#pragma unroll
        for (int r = 0; r < 16; ++r) { st0[r] = 0.f; st1[r] = 0.f; }
        int k0 = l31, k1 = 32 + l31;
#pragma unroll
        for (int ds = 0; ds < 8; ++ds) {
            int sw = ((ds * 2 + hi) ^ (l31 & 7)) << 3;
            short8 kf0 = *(const short8*)(ktb + (k0 << 7) + sw);
            short8 kf1 = *(const short8*)(ktb + (k1 << 7) + sw);
            st0 = __builtin_amdgcn_mfma_f32_32x32x16_bf16(kf0, qf[ds], st0, 0, 0, 0);
            st1 = __builtin_amdgcn_mfma_f32_32x32x16_bf16(kf1, qf[ds], st1, 0, 0, 0);
        }
        if (t == nt - 1) {                      // tail: replace (kills garbage NaN/Inf)
#pragma unroll
            for (int r = 0; r < 16; ++r) {
                int kl = (r & 3) + 8 * (r >> 2) + 4 * hi;
                st0[r] = (t * 64 + kl < L) ? st0[r] : -1e30f;
                st1[r] = (t * 64 + 32 + kl < L) ? st1[r] : -1e30f;
            }
        }
        float mx = st0[0];
#pragma unroll
        for (int r = 1; r < 16; ++r) mx = fmaxf(mx, st0[r]);
#pragma unroll
        for (int r = 0; r < 16; ++r) mx = fmaxf(mx, st1[r]);
        mx = fmaxf(mx, __shfl_xor(mx, 32));
        if (__any(mx - m > 11.0f)) {            // defer-max (log2 units)
            float mn = fmaxf(m, mx);
            float corr = fexp2(m - mn);
            m = mn;
            lsum *= corr;
#pragma unroll
            for (int r = 0; r < 16; ++r) {
                float cc = __shfl(corr, (r & 3) + 8 * (r >> 2) + 4 * hi);
                o[0][r] *= cc; o[1][r] *= cc; o[2][r] *= cc; o[3][r] *= cc;
            }
        }
        float p0a[16], p1a[16];
#pragma unroll
        for (int r = 0; r < 16; ++r) { p0a[r] = fexp2(st0[r] - m); p1a[r] = fexp2(st1[r] - m); }
        float s0 = 0.f, s1 = 0.f, s2 = 0.f, s3 = 0.f;
#pragma unroll
        for (int r = 0; r < 16; r += 4) {
            s0 += p0a[r]; s1 += p0a[r + 1]; s2 += p0a[r + 2]; s3 += p0a[r + 3];
            s0 += p1a[r]; s1 += p1a[r + 1]; s2 += p1a[r + 2]; s3 += p1a[r + 3];
        }
        float tot = (s0 + s1) + (s2 + s3);
        tot += __shfl_xor(tot, 32);
        lsum += tot;
        short8 pa0 = make_pa(p0a[0], p0a[1], p0a[2], p0a[3], p0a[4], p0a[5], p0a[6], p0a[7]);
        short8 pa1 = make_pa(p0a[8], p0a[9], p0a[10], p0a[11], p0a[12], p0a[13], p0a[14], p0a[15]);
        short8 pa2 = make_pa(p1a[0], p1a[1], p1a[2], p1a[3], p1a[4], p1a[5], p1a[6], p1a[7]);
        short8 pa3 = make_pa(p1a[8], p1a[9], p1a[10], p1a[11], p1a[12], p1a[13], p1a[14], p1a[15]);
        // O += P @ V ; V chunk-major (linear, conflict-free)
#pragma unroll
        for (int dblk = 0; dblk < 4; ++dblk) {
#pragma unroll
            for (int ks = 0; ks < 4; ++ks) {
                short8 vf = *(const short8*)(vtb +
                    ((((ks * 2 + hi) << 7) + (dblk << 5) + l31) << 3));
                short8 pa = (ks == 0) ? pa0 : (ks == 1) ? pa1 : (ks == 2) ? pa2 : pa3;
                o[dblk] = __builtin_amdgcn_mfma_f32_32x32x16_bf16(pa, vf, o[dblk], 0, 0, 0);
            }
        }
        __syncthreads();
        cur ^= 1;
    }

    // ---- fused epilogue: stage 32x1024 attn-out into LDS, chunk-major (conflict-free) ----
    // epi[(cw*32 + row)*8 + slot], cw = column-chunk (f/8), row = local mha row, slot = f&7
    u16* epi = smem;
    float invl = 1.0f / lsum;
#pragma unroll
    for (int r = 0; r < 16; ++r) {
        int kl = (r & 3) + 8 * (r >> 2) + 4 * hi;
        float iv = __shfl(invl, kl);
        int row_local = w * 4 + (kl >> 3);
        int cb2 = (kl & 7) * 16 + (l31 >> 3);
#pragma unroll
        for (int dblk = 0; dblk < 4; ++dblk) {
            int cw = cb2 + dblk * 4;
            epi[(cw * 32 + row_local) * 8 + (l31 & 7)] = f2bf(o[dblk][r] * iv);
        }
    }
    __syncthreads();

    // ---- W_fc GEMM (K=1024 from epi) + residual Q@W_in (K=64), parity-split accs ----
    const int rg = w >> 2, cg = w & 3;           // 2 rowgroups x 4 colgroups
    const int srow0 = h * 256 + qt * 32;
    const int row16 = rg * 16 + c15;
    f32x4 acA[2], acB[2];
    acA[0] = {0.f, 0.f, 0.f, 0.f}; acA[1] = {0.f, 0.f, 0.f, 0.f};
    acB[0] = {0.f, 0.f, 0.f, 0.f}; acB[1] = {0.f, 0.f, 0.f, 0.f};
    {   // residual -> acA
        const float* p0 = Qin + ((size_t)b * 2048 + srow0 + row16) * 64;
        short8 af2[2];
#pragma unroll
        for (int c = 0; c < 2; ++c) {
            float4 fa = *(const float4*)(p0 + 8 * g + 32 * c);
            float4 fb = *(const float4*)(p0 + 8 * g + 32 * c + 4);
            short8 a;
            a[0] = (short)f2bf(fa.x); a[1] = (short)f2bf(fa.y);
            a[2] = (short)f2bf(fa.z); a[3] = (short)f2bf(fa.w);
            a[4] = (short)f2bf(fb.x); a[5] = (short)f2bf(fb.y);
            a[6] = (short)f2bf(fb.z); a[7] = (short)f2bf(fb.w);
            af2[c] = a;
        }
#pragma unroll
        for (int eb = 0; eb < 2; ++eb)
#pragma unroll
            for (int c = 0; c < 2; ++c) {
                short8 bfr = *(const short8*)(win16 +
                    (size_t)(cg * 32 + eb * 16 + c15) * 64 + 8 * g + 32 * c);
                acA[eb] = __builtin_amdgcn_mfma_f32_16x16x32_bf16(af2[c], bfr, acA[eb], 0, 0, 0);
            }
    }
#pragma unroll
    for (int kc2 = 0; kc2 < 16; ++kc2) {
        int kcE = 2 * kc2, kcO = 2 * kc2 + 1;
        short8 afE = *(const short8*)(epi + ((kcE * 4 + g) * 32 + row16) * 8);
        short8 afO = *(const short8*)(epi + ((kcO * 4 + g) * 32 + row16) * 8);
#pragma unroll
        for (int eb = 0; eb < 2; ++eb) {
            short8 bfE = *(const short8*)(wfc16 +
                (size_t)(cg * 32 + eb * 16 + c15) * 1024 + kcE * 32 + 8 * g);
            short8 bfO = *(const short8*)(wfc16 +
                (size_t)(cg * 32 + eb * 16 + c15) * 1024 + kcO * 32 + 8 * g);
            acA[eb] = __builtin_amdgcn_mfma_f32_16x16x32_bf16(afE, bfE, acA[eb], 0, 0, 0);
            acB[eb] = __builtin_amdgcn_mfma_f32_16x16x32_bf16(afO, bfO, acB[eb], 0, 0, 0);
        }
    }
    f32x4 acc2[2];
#pragma unroll
    for (int eb = 0; eb < 2; ++eb)
#pragma unroll
        for (int r = 0; r < 4; ++r)
            acc2[eb][r] = acA[eb][r] + acB[eb][r];
    // ---- LN partials across colgroups ----
#pragma unroll
    for (int r = 0; r < 4; ++r) {
        float s = acc2[0][r] + acc2[1][r];
        float q2 = acc2[0][r] * acc2[0][r] + acc2[1][r] * acc2[1][r];
#pragma unroll
        for (int dd = 1; dd < 16; dd <<= 1) {
            s += __shfl_xor(s, dd);
            q2 += __shfl_xor(q2, dd);
        }
        if (c15 == 0) pls[rg * 16 + 4 * g + r][cg] = make_float2(s, q2);
    }
    __syncthreads();
    float gg0 = ln_g[cg * 32 + c15],      bb0 = ln_b[cg * 32 + c15];
    float gg1 = ln_g[cg * 32 + 16 + c15], bb1 = ln_b[cg * 32 + 16 + c15];
#pragma unroll
    for (int r = 0; r < 4; ++r) {
        int row = rg * 16 + 4 * g + r;
        float2 pa = pls[row][0], pb = pls[row][1], pc = pls[row][2], pd = pls[row][3];
        float mean = (pa.x + pb.x + pc.x + pd.x) * (1.0f / 128.0f);
        float var  = (pa.y + pb.y + pc.y + pd.y) * (1.0f / 128.0f) - mean * mean;
        float rstd = rsqrtf(var + 1e-6f);
        size_t ob = ((size_t)b * 2048 + srow0 + row) * 128;
        out[ob + cg * 32 + c15]      = (acc2[0][r] - mean) * rstd * gg0 + bb0;
        out[ob + cg * 32 + 16 + c15] = (acc2[1][r] - mean) * rstd * gg1 + bb1;
    }
}

// ---------- launcher ----------
extern "C" void kernel_launch(void* const* d_in, const int* in_sizes, int n_in,
                              void* d_out, int out_size, void* d_ws, size_t ws_size,
                              hipStream_t stream) {
    const float* Q     = (const float*)d_in[0];
    const float* K     = (const float*)d_in[1];
    const float* V     = (const float*)d_in[2];
    const float* QMask = (const float*)d_in[3];
    const float* W_in  = (const float*)d_in[4];
    const float* W_mh  = (const float*)d_in[5];
    const float* W_fc  = (const float*)d_in[6];
    const float* ln_g  = (const float*)d_in[7];
    const float* ln_b  = (const float*)d_in[8];
    float* out = (float*)d_out;

    char* ws = (char*)d_ws;
    u16*   wcomb = (u16*)(ws);                   // 131072 B
    u16*   wfc16 = (u16*)(ws + 131072);          // 262144 B
    u16*   kb    = (u16*)(ws + 42336256);        // compacted K rows [B*H,S,128]
    u16*   vT    = (u16*)(ws + 75890688);        // chunk-major [B*H][256 kcg][128 d][8]
    u16*   vrow  = (u16*)(ws + 109445120);       // compacted V rows (consumed by vtrans)
    u16*   pos   = (u16*)(ws + 142999552);       // [B,S] compact position or 0xFFFF
    int*   cnt   = (int*)(ws + 143032320);       // [B] unmasked counts
    u16*   win16 = (u16*)(ws + 143036416);       // W_in bf16 [128][64]

    hipLaunchKernelGGL(prep_kernel, dim3(808), dim3(256), 0, stream,
                       W_in, W_mh, W_fc, QMask, wcomb, wfc16, win16, pos, cnt);
    hipLaunchKernelGGL(qkv_kernel, dim3(256, 4, 2), dim3(256), 0, stream,
                       K, V, wcomb, pos, kb, vrow);
    hipLaunchKernelGGL(vtrans_kernel, dim3(32, 64), dim3(256), 0, stream,
                       vrow, cnt, vT);
    hipLaunchKernelGGL(attn_kernel, dim3(64, 8), dim3(512), 0, stream,
                       Q, wcomb, kb, vT, cnt, wfc16, win16, ln_g, ln_b, out);
}

// Round 12
// 174.218 us; speedup vs baseline: 1.0317x; 1.0132x over previous
//
#include <hip/hip_runtime.h>
#include <hip/hip_bf16.h>
#include <cstdint>

typedef __attribute__((ext_vector_type(8))) short short8;
typedef __attribute__((ext_vector_type(4))) float f32x4;
typedef __attribute__((ext_vector_type(16))) float f32x16;
typedef unsigned short u16;
typedef unsigned int u32;

__device__ __forceinline__ u16 f2bf(float f) {
    union { float f; u32 u; } v; v.f = f;
    u32 u = v.u;
    u = (u + 0x7fffu + ((u >> 16) & 1u)) >> 16;
    return (u16)u;
}

__device__ __forceinline__ float fexp2(float x) {   // v_exp_f32 = 2^x
    float r;
    asm("v_exp_f32 %0, %1" : "=v"(r) : "v"(x));
    return r;
}

__device__ __forceinline__ u32 pk_bf16(float lo, float hi) {
    u32 r;
    asm("v_cvt_pk_bf16_f32 %0, %1, %2" : "=v"(r) : "v"(lo), "v"(hi));
    return r;
}

__device__ __forceinline__ void pl32swap(u32& a, u32& b) {
#if __has_builtin(__builtin_amdgcn_permlane32_swap)
    auto r = __builtin_amdgcn_permlane32_swap((int)a, (int)b, false, false);
    a = (u32)r[0]; b = (u32)r[1];
#else
    u32 ax = (u32)__shfl_xor((int)a, 32), bx = (u32)__shfl_xor((int)b, 32);
    bool hi = (threadIdx.x & 32) != 0;
    u32 na = hi ? bx : a;
    u32 nb = hi ? b : ax;
    a = na; b = nb;
#endif
}

__device__ __forceinline__ void gload_lds16(const u16* g, u16* l) {
    __builtin_amdgcn_global_load_lds((const __attribute__((address_space(1))) void*)g,
                                     (__attribute__((address_space(3))) void*)l, 16, 0, 0);
}

// C-block rows (crow order) -> one 16-k A/B-frag via cvt_pk + permlane32_swap (T12)
__device__ __forceinline__ short8 make_pa(float p0, float p1, float p2, float p3,
                                          float p4, float p5, float p6, float p7) {
    u32 a1 = pk_bf16(p0, p1), b1 = pk_bf16(p4, p5);
    u32 a2 = pk_bf16(p2, p3), b2 = pk_bf16(p6, p7);
    pl32swap(a1, b1); pl32swap(a2, b2);
    union { u32 w[4]; short8 s; } u;
    u.w[0] = a1; u.w[1] = a2; u.w[2] = b1; u.w[3] = b2;
    return u.s;
}

// ---------- kernel 0: weights prep (blocks 0..799) + mask scan (blocks 800..807) ----------
__global__ void prep_kernel(const float* __restrict__ W_in,
                            const float* __restrict__ W_mh,
                            const float* __restrict__ W_fc,
                            const float* __restrict__ qmask,
                            u16* __restrict__ wcomb, u16* __restrict__ wfc16,
                            u16* __restrict__ win16,
                            u16* __restrict__ pos, int* __restrict__ cnt) {
    if (blockIdx.x >= 800) {                     // per-batch stable compaction scan
        if (threadIdx.x >= 64) return;
        int b = blockIdx.x - 800, t = threadIdx.x;
        int base = b * 2048 + t * 32;
        int c = 0;
#pragma unroll
        for (int i = 0; i < 32; ++i) c += (qmask[base + i] != 0.0f) ? 1 : 0;
        int inc = c;
#pragma unroll
        for (int dd = 1; dd < 64; dd <<= 1) {
            int v = __shfl_up(inc, dd);
            if (t >= dd) inc += v;
        }
        int run = inc - c;
#pragma unroll
        for (int i = 0; i < 32; ++i) {
            bool mk = (qmask[base + i] != 0.0f);
            pos[base + i] = mk ? (u16)run : (u16)0xFFFF;
            run += mk ? 1 : 0;
        }
        if (t == 63) cnt[b] = inc;
        return;
    }
    int idx = blockIdx.x * 256 + threadIdx.x;
    if (idx < 1024 * 64) {                       // W_comb = W_mh @ W_in
        int f = idx >> 6, i = idx & 63;
        float acc = 0.f;
        for (int e = 0; e < 128; ++e)
            acc += W_mh[f * 128 + e] * W_in[e * 64 + i];
        wcomb[idx] = f2bf(acc);
    }
    int idx2 = idx - 65536;
    if (idx2 >= 0 && idx2 < 128 * 1024) {
        // wfc16 stored in PERMUTED k-order: k' = sub*128 + l31*4 + dblk
        // (orig k = sub*128 + dblk*32 + l31). Matches attn epilogue's epi layout.
        int e = idx2 >> 10, fp = idx2 & 1023;
        int sub = fp >> 7, r2 = fp & 127;
        int forig = sub * 128 + (r2 & 3) * 32 + (r2 >> 2);
        wfc16[idx2] = f2bf(W_fc[e * 1024 + forig]);
    }
    int idx3 = idx - 65536 - 131072;
    if (idx3 >= 0 && idx3 < 128 * 64)
        win16[idx3] = f2bf(W_in[idx3]);
}

// ---------- kernel 1: k/v projections, compacted rows, LDS-staged 16B stores ----------
__global__ __launch_bounds__(256) void qkv_kernel(
    const float* __restrict__ K, const float* __restrict__ V,
    const u16* __restrict__ wcomb, const u16* __restrict__ pos,
    u16* __restrict__ kb, u16* __restrict__ vrow) {
    __shared__ __align__(16) u16 ot[64 * 264];
    int w = threadIdx.x >> 6, lane = threadIdx.x & 63;
    int g = lane >> 4, c15 = lane & 15;
    const float* X = blockIdx.z == 0 ? K : V;

    int Rrow = blockIdx.x * 64 + w * 16 + c15;
    short8 af[2];
#pragma unroll
    for (int c = 0; c < 2; ++c) {
        const float* p = X + (size_t)Rrow * 64 + 8 * g + 32 * c;
        float4 fa = *(const float4*)(p);
        float4 fb = *(const float4*)(p + 4);
        short8 a;
        a[0] = (short)f2bf(fa.x); a[1] = (short)f2bf(fa.y);
        a[2] = (short)f2bf(fa.z); a[3] = (short)f2bf(fa.w);
        a[4] = (short)f2bf(fb.x); a[5] = (short)f2bf(fb.y);
        a[6] = (short)f2bf(fb.z); a[7] = (short)f2bf(fb.w);
        af[c] = a;
    }
    int colbase = blockIdx.y * 256;
    f32x4 acc[16];
#pragma unroll
    for (int i = 0; i < 16; ++i) acc[i] = {0.f, 0.f, 0.f, 0.f};
#pragma unroll
    for (int cb = 0; cb < 16; ++cb) {
        int col = colbase + cb * 16 + c15;
#pragma unroll
        for (int c = 0; c < 2; ++c) {
            short8 bfr = *(const short8*)(wcomb + (size_t)col * 64 + 8 * g + 32 * c);
            acc[cb] = __builtin_amdgcn_mfma_f32_16x16x32_bf16(af[c], bfr, acc[cb], 0, 0, 0);
        }
    }
    int r0 = w * 16 + 4 * g;
#pragma unroll
    for (int cb = 0; cb < 16; ++cb)
#pragma unroll
        for (int r = 0; r < 4; ++r)
            ot[(r0 + r) * 264 + cb * 16 + c15] = f2bf(acc[cb][r]);
    __syncthreads();
    u16* dstbuf = blockIdx.z == 0 ? kb : vrow;
#pragma unroll
    for (int it = 0; it < 8; ++it) {
        int chunk = threadIdx.x + it * 256;
        int row = chunk >> 5, cc = chunk & 31;
        int R = blockIdx.x * 64 + row;
        u16 p = pos[R];
        if (p != 0xFFFF) {
            int b = R >> 11;
            int col0 = colbase + cc * 8;
            int h = col0 >> 7, d = col0 & 127;
            *(uint4*)(dstbuf + ((size_t)(b * 8 + h) * 2048 + p) * 128 + d) =
                *(const uint4*)(ot + row * 264 + cc * 8);
        }
    }
}

// ---------- kernel 2: transpose compacted V rows -> chunk-major vT[bh][kcg][128][8] ----------
__global__ __launch_bounds__(256) void vtrans_kernel(
    const u16* __restrict__ vrow, const int* __restrict__ cnt,
    u16* __restrict__ vT) {
    int t = blockIdx.x, bh = blockIdx.y, b = bh >> 3;
    int L = cnt[b];
    if (t * 64 >= L) return;
    __shared__ __align__(16) u32 tl[128 * 32];   // [d][32 s-pairs], chunk-XOR swizzled
    const u16* src = vrow + ((size_t)bh * 2048 + t * 64) * 128;
#pragma unroll
    for (int task = 0; task < 2; ++task) {
        int id = threadIdx.x + task * 256;       // 512 tasks: s-pair i x d-chunk c
        int i = id >> 4, c = id & 15;
        int r0 = 2 * i, r1 = 2 * i + 1;
        uint4 A = {0, 0, 0, 0}, Bv = {0, 0, 0, 0};
        if (t * 64 + r0 < L) A  = *(const uint4*)(src + (size_t)r0 * 128 + c * 8);
        if (t * 64 + r1 < L) Bv = *(const uint4*)(src + (size_t)r1 * 128 + c * 8);
        const u32* aw = (const u32*)&A;
        const u32* bw = (const u32*)&Bv;
#pragma unroll
        for (int j = 0; j < 4; ++j) {
            u32 lo  = (aw[j] & 0xFFFFu) | (bw[j] << 16);       // d=8c+2j,  rows (r0,r1)
            u32 hi2 = (aw[j] >> 16) | (bw[j] & 0xFFFF0000u);   // d=8c+2j+1
            int d0 = 8 * c + 2 * j, d1 = d0 + 1;
            int h0 = ((d0 & 7) ^ ((d0 >> 3) & 7)) << 2;
            int h1 = ((d1 & 7) ^ ((d1 >> 3) & 7)) << 2;
            tl[d0 * 32 + (i ^ h0)] = lo;
            tl[d1 * 32 + (i ^ h1)] = hi2;
        }
    }
    __syncthreads();
    int d = threadIdx.x >> 1, half = threadIdx.x & 1;
    int hd = (d & 7) ^ ((d >> 3) & 7);
#pragma unroll
    for (int jc = 0; jc < 4; ++jc) {
        int chunk = (half * 4 + jc) ^ hd;
        int kcg = t * 8 + half * 4 + jc;         // global 8-key chunk index
        *(uint4*)(vT + (((size_t)bh * 256 + kcg) * 128 + d) * 8) =
            *(const uint4*)(&tl[d * 32 + chunk * 4]);
    }
}

// ---------- kernel 3: flash attn (r5 structure) + fused W_fc GEMM + residual + LN ----------
__global__ __launch_bounds__(512, 2) void attn_kernel(
    const float* __restrict__ Qin, const u16* __restrict__ wcomb,
    const u16* __restrict__ kbuf, const u16* __restrict__ vTc,
    const int* __restrict__ cnt,
    const u16* __restrict__ wfc16, const u16* __restrict__ win16,
    const float* __restrict__ ln_g, const float* __restrict__ ln_b,
    float* __restrict__ out) {
    __shared__ __align__(16) u16 smem[32768];    // kt[2][8192] | vt[2][8192]; epi overlay
    __shared__ float2 pls[32][4];                // LN partials: [row][colgroup] (sum, sumsq)

    const int w = threadIdx.x >> 6, lane = threadIdx.x & 63;
    const int hi = lane >> 5, l31 = lane & 31;
    const int g = lane >> 4, c15 = lane & 15;
    const int bh = blockIdx.x, qt = blockIdx.y;  // XCD = bh%8: all qt of a bh share L2
    const int b = bh >> 3, h = bh & 7;
    const int L = cnt[b];
    const int nt = (L + 63) >> 6;

    const u16* kbbh = kbuf + (size_t)bh * 2048 * 128;
    const u16* vTbh = vTc + (size_t)bh * 262144; // 256 kcg * 128 d * 8

    u16* ktb0 = smem;                            // [2][8192]
    u16* vtb0 = smem + 16384;                    // [2][8192] chunk-major: (kcg*128+d)*8

    auto stage = [&](int buf, int tt) {
#pragma unroll
        for (int c = 0; c < 2; ++c) {
            int rl = (c * 8 + w) * 4 + (lane >> 4);     // K: 4 rows per wave-call
            int ck = (lane & 15) ^ (rl & 7);
            gload_lds16(kbbh + ((size_t)(tt * 64 + rl)) * 128 + ck * 8,
                        ktb0 + buf * 8192 + (c * 8 + w) * 512);
            int ci = c * 512 + w * 64 + lane;           // V: pure linear block copy
            gload_lds16(vTbh + ((size_t)tt * 1024 + ci) * 8,
                        vtb0 + buf * 8192 + (c * 512 + w * 64) * 8);
        }
    };

    stage(0, 0);                                 // DMA overlaps q-projection below

    // ---- fused q-projection, scaled by log2(e)/sqrt(128) (softmax in log2 domain) ----
    const float invT2 = 0.12751743f;             // log2(e)/sqrt(128)
    const int q0 = qt * 256 + w * 32;
    const float* qrow = Qin + ((size_t)b * 2048 + q0 + l31) * 64;
    short8 bq[4];
#pragma unroll
    for (int s = 0; s < 4; ++s) {
        const float* p = qrow + s * 16 + hi * 8;
        float4 fa = *(const float4*)(p);
        float4 fb = *(const float4*)(p + 4);
        short8 a;
        a[0] = (short)f2bf(fa.x); a[1] = (short)f2bf(fa.y);
        a[2] = (short)f2bf(fa.z); a[3] = (short)f2bf(fa.w);
        a[4] = (short)f2bf(fb.x); a[5] = (short)f2bf(fb.y);
        a[6] = (short)f2bf(fb.z); a[7] = (short)f2bf(fb.w);
        bq[s] = a;
    }
    short8 qf[8];
#pragma unroll
    for (int dblk = 0; dblk < 4; ++dblk) {
        f32x16 c2;
#pragma unroll
        for (int r = 0; r < 16; ++r) c2[r] = 0.f;
        const u16* wrow = wcomb + (size_t)(h * 128 + dblk * 32 + l31) * 64 + hi * 8;
#pragma unroll
        for (int s = 0; s < 4; ++s) {
            short8 wa = *(const short8*)(wrow + s * 16);
            c2 = __builtin_amdgcn_mfma_f32_32x32x16_bf16(wa, bq[s], c2, 0, 0, 0);
        }
        qf[2 * dblk] = make_pa(c2[0] * invT2, c2[1] * invT2, c2[2] * invT2, c2[3] * invT2,
                               c2[4] * invT2, c2[5] * invT2, c2[6] * invT2, c2[7] * invT2);
        qf[2 * dblk + 1] = make_pa(c2[8] * invT2, c2[9] * invT2, c2[10] * invT2, c2[11] * invT2,
                                   c2[12] * invT2, c2[13] * invT2, c2[14] * invT2, c2[15] * invT2);
    }

    f32x16 o[4];
#pragma unroll
    for (int i = 0; i < 4; ++i)
#pragma unroll
        for (int r = 0; r < 16; ++r) o[i][r] = 0.f;
    float m = -1e30f, lsum = 0.f;

    int cur = 0;
    __syncthreads();

    for (int t = 0; t < nt; ++t) {
        if (t + 1 < nt) stage(cur ^ 1, t + 1);
        const u16* ktb = ktb0 + cur * 8192;
        const u16* vtb = vtb0 + cur * 8192;

        // S^T = K . Q^T (log2 domain)
        f32x16 st0, st1;
#pragma unroll
        for (int r = 0; r < 16; ++r) { st0[r] = 0.f; st1[r] = 0.f; }
        int k0 = l31, k1 = 32 + l31;
#pragma unroll
        for (int ds = 0; ds < 8; ++ds) {
            int sw = ((ds * 2 + hi) ^ (l31 & 7)) << 3;
            short8 kf0 = *(const short8*)(ktb + (k0 << 7) + sw);
            short8 kf1 = *(const short8*)(ktb + (k1 << 7) + sw);
            st0 = __builtin_amdgcn_mfma_f32_32x32x16_bf16(kf0, qf[ds], st0, 0, 0, 0);
            st1 = __builtin_amdgcn_mfma_f32_32x32x16_bf16(kf1, qf[ds], st1, 0, 0, 0);
        }
        if (t == nt - 1) {                      // tail: replace (kills garbage NaN/Inf)
#pragma unroll
            for (int r = 0; r < 16; ++r) {
                int kl = (r & 3) + 8 * (r >> 2) + 4 * hi;
                st0[r] = (t * 64 + kl < L) ? st0[r] : -1e30f;
                st1[r] = (t * 64 + 32 + kl < L) ? st1[r] : -1e30f;
            }
        }
        float mx = st0[0];
#pragma unroll
        for (int r = 1; r < 16; ++r) mx = fmaxf(mx, st0[r]);
#pragma unroll
        for (int r = 0; r < 16; ++r) mx = fmaxf(mx, st1[r]);
        mx = fmaxf(mx, __shfl_xor(mx, 32));
        if (__any(mx - m > 11.0f)) {            // defer-max (log2 units)
            float mn = fmaxf(m, mx);
            float corr = fexp2(m - mn);
            m = mn;
            lsum *= corr;
#pragma unroll
            for (int r = 0; r < 16; ++r) {
                float cc = __shfl(corr, (r & 3) + 8 * (r >> 2) + 4 * hi);
                o[0][r] *= cc; o[1][r] *= cc; o[2][r] *= cc; o[3][r] *= cc;
            }
        }
        float p0a[16], p1a[16];
#pragma unroll
        for (int r = 0; r < 16; ++r) { p0a[r] = fexp2(st0[r] - m); p1a[r] = fexp2(st1[r] - m); }
        float s0 = 0.f, s1 = 0.f, s2 = 0.f, s3 = 0.f;
#pragma unroll
        for (int r = 0; r < 16; r += 4) {
            s0 += p0a[r]; s1 += p0a[r + 1]; s2 += p0a[r + 2]; s3 += p0a[r + 3];
            s0 += p1a[r]; s1 += p1a[r + 1]; s2 += p1a[r + 2]; s3 += p1a[r + 3];
        }
        float tot = (s0 + s1) + (s2 + s3);
        tot += __shfl_xor(tot, 32);
        lsum += tot;
        short8 pa0 = make_pa(p0a[0], p0a[1], p0a[2], p0a[3], p0a[4], p0a[5], p0a[6], p0a[7]);
        short8 pa1 = make_pa(p0a[8], p0a[9], p0a[10], p0a[11], p0a[12], p0a[13], p0a[14], p0a[15]);
        short8 pa2 = make_pa(p1a[0], p1a[1], p1a[2], p1a[3], p1a[4], p1a[5], p1a[6], p1a[7]);
        short8 pa3 = make_pa(p1a[8], p1a[9], p1a[10], p1a[11], p1a[12], p1a[13], p1a[14], p1a[15]);
        // O += P @ V ; V chunk-major (linear, conflict-free)
#pragma unroll
        for (int dblk = 0; dblk < 4; ++dblk) {
#pragma unroll
            for (int ks = 0; ks < 4; ++ks) {
                short8 vf = *(const short8*)(vtb +
                    ((((ks * 2 + hi) << 7) + (dblk << 5) + l31) << 3));
                short8 pa = (ks == 0) ? pa0 : (ks == 1) ? pa1 : (ks == 2) ? pa2 : pa3;
                o[dblk] = __builtin_amdgcn_mfma_f32_32x32x16_bf16(pa, vf, o[dblk], 0, 0, 0);
            }
        }
        __syncthreads();
        cur ^= 1;
    }

    // ---- fused epilogue: stage 32x1024 attn-out into LDS in PERMUTED k'-order ----
    // k' = (kl&7)*128 + l31*4 + dblk  (wfc16 stores matching permutation).
    // Per lane: 4 contiguous bf16 -> one ds_write_b64. XOR-swizzle 16B chunks by row&7.
    u16* epi = smem;
    float invl = 1.0f / lsum;
#pragma unroll
    for (int r = 0; r < 16; ++r) {
        int kl = (r & 3) + 8 * (r >> 2) + 4 * hi;
        float iv = __shfl(invl, kl);
        int row_local = w * 4 + (kl >> 3);
        u32 w0 = pk_bf16(o[0][r] * iv, o[1][r] * iv);
        u32 w1 = pk_bf16(o[2][r] * iv, o[3][r] * iv);
        int chunk16 = (kl & 7) * 16 + (l31 >> 1);
        int idx = row_local * 1024 + ((chunk16 ^ (row_local & 7)) << 3) + (l31 & 1) * 4;
        *(uint2*)(epi + idx) = make_uint2(w0, w1);
    }
    __syncthreads();

    // ---- W_fc GEMM (K=1024 from epi, permuted k') + residual Q@W_in (K=64) ----
    const int rg = w >> 2, cg = w & 3;           // 2 rowgroups x 4 colgroups
    const int srow0 = h * 256 + qt * 32;
    const int row16 = rg * 16 + c15;
    f32x4 acA[2], acB[2];
    acA[0] = {0.f, 0.f, 0.f, 0.f}; acA[1] = {0.f, 0.f, 0.f, 0.f};
    acB[0] = {0.f, 0.f, 0.f, 0.f}; acB[1] = {0.f, 0.f, 0.f, 0.f};
    {   // residual -> acA
        const float* p0 = Qin + ((size_t)b * 2048 + srow0 + row16) * 64;
        short8 af2[2];
#pragma unroll
        for (int c = 0; c < 2; ++c) {
            float4 fa = *(const float4*)(p0 + 8 * g + 32 * c);
            float4 fb = *(const float4*)(p0 + 8 * g + 32 * c + 4);
            short8 a;
            a[0] = (short)f2bf(fa.x); a[1] = (short)f2bf(fa.y);
            a[2] = (short)f2bf(fa.z); a[3] = (short)f2bf(fa.w);
            a[4] = (short)f2bf(fb.x); a[5] = (short)f2bf(fb.y);
            a[6] = (short)f2bf(fb.z); a[7] = (short)f2bf(fb.w);
            af2[c] = a;
        }
#pragma unroll
        for (int eb = 0; eb < 2; ++eb)
#pragma unroll
            for (int c = 0; c < 2; ++c) {
                short8 bfr = *(const short8*)(win16 +
                    (size_t)(cg * 32 + eb * 16 + c15) * 64 + 8 * g + 32 * c);
                acA[eb] = __builtin_amdgcn_mfma_f32_16x16x32_bf16(af2[c], bfr, acA[eb], 0, 0, 0);
            }
    }
    const int rsw = row16 & 7;
#pragma unroll
    for (int kc2 = 0; kc2 < 16; ++kc2) {
        int kcE = 2 * kc2, kcO = 2 * kc2 + 1;
        short8 afE = *(const short8*)(epi + row16 * 1024 + (((kcE * 4 + g) ^ rsw) << 3));
        short8 afO = *(const short8*)(epi + row16 * 1024 + (((kcO * 4 + g) ^ rsw) << 3));
#pragma unroll
        for (int eb = 0; eb < 2; ++eb) {
            short8 bfE = *(const short8*)(wfc16 +
                (size_t)(cg * 32 + eb * 16 + c15) * 1024 + kcE * 32 + 8 * g);
            short8 bfO = *(const short8*)(wfc16 +
                (size_t)(cg * 32 + eb * 16 + c15) * 1024 + kcO * 32 + 8 * g);
            acA[eb] = __builtin_amdgcn_mfma_f32_16x16x32_bf16(afE, bfE, acA[eb], 0, 0, 0);
            acB[eb] = __builtin_amdgcn_mfma_f32_16x16x32_bf16(afO, bfO, acB[eb], 0, 0, 0);
        }
    }
    f32x4 acc2[2];
#pragma unroll
    for (int eb = 0; eb < 2; ++eb)
#pragma unroll
        for (int r = 0; r < 4; ++r)
            acc2[eb][r] = acA[eb][r] + acB[eb][r];
    // ---- LN partials across colgroups ----
#pragma unroll
    for (int r = 0; r < 4; ++r) {
        float s = acc2[0][r] + acc2[1][r];
        float q2 = acc2[0][r] * acc2[0][r] + acc2[1][r] * acc2[1][r];
#pragma unroll
        for (int dd = 1; dd < 16; dd <<= 1) {
            s += __shfl_xor(s, dd);
            q2 += __shfl_xor(q2, dd);
        }
        if (c15 == 0) pls[rg * 16 + 4 * g + r][cg] = make_float2(s, q2);
    }
    __syncthreads();
    float gg0 = ln_g[cg * 32 + c15],      bb0 = ln_b[cg * 32 + c15];
    float gg1 = ln_g[cg * 32 + 16 + c15], bb1 = ln_b[cg * 32 + 16 + c15];
#pragma unroll
    for (int r = 0; r < 4; ++r) {
        int row = rg * 16 + 4 * g + r;
        float2 pa = pls[row][0], pb = pls[row][1], pc = pls[row][2], pd = pls[row][3];
        float mean = (pa.x + pb.x + pc.x + pd.x) * (1.0f / 128.0f);
        float var  = (pa.y + pb.y + pc.y + pd.y) * (1.0f / 128.0f) - mean * mean;
        float rstd = rsqrtf(var + 1e-6f);
        size_t ob = ((size_t)b * 2048 + srow0 + row) * 128;
        out[ob + cg * 32 + c15]      = (acc2[0][r] - mean) * rstd * gg0 + bb0;
        out[ob + cg * 32 + 16 + c15] = (acc2[1][r] - mean) * rstd * gg1 + bb1;
    }
}

// ---------- launcher ----------
extern "C" void kernel_launch(void* const* d_in, const int* in_sizes, int n_in,
                              void* d_out, int out_size, void* d_ws, size_t ws_size,
                              hipStream_t stream) {
    const float* Q     = (const float*)d_in[0];
    const float* K     = (const float*)d_in[1];
    const float* V     = (const float*)d_in[2];
    const float* QMask = (const float*)d_in[3];
    const float* W_in  = (const float*)d_in[4];
    const float* W_mh  = (const float*)d_in[5];
    const float* W_fc  = (const float*)d_in[6];
    const float* ln_g  = (const float*)d_in[7];
    const float* ln_b  = (const float*)d_in[8];
    float* out = (float*)d_out;

    char* ws = (char*)d_ws;
    u16*   wcomb = (u16*)(ws);                   // 131072 B
    u16*   wfc16 = (u16*)(ws + 131072);          // 262144 B (k'-permuted)
    u16*   kb    = (u16*)(ws + 42336256);        // compacted K rows [B*H,S,128]
    u16*   vT    = (u16*)(ws + 75890688);        // chunk-major [B*H][256 kcg][128 d][8]
    u16*   vrow  = (u16*)(ws + 109445120);       // compacted V rows (consumed by vtrans)
    u16*   pos   = (u16*)(ws + 142999552);       // [B,S] compact position or 0xFFFF
    int*   cnt   = (int*)(ws + 143032320);       // [B] unmasked counts
    u16*   win16 = (u16*)(ws + 143036416);       // W_in bf16 [128][64]

    hipLaunchKernelGGL(prep_kernel, dim3(808), dim3(256), 0, stream,
                       W_in, W_mh, W_fc, QMask, wcomb, wfc16, win16, pos, cnt);
    hipLaunchKernelGGL(qkv_kernel, dim3(256, 4, 2), dim3(256), 0, stream,
                       K, V, wcomb, pos, kb, vrow);
    hipLaunchKernelGGL(vtrans_kernel, dim3(32, 64), dim3(256), 0, stream,
                       vrow, cnt, vT);
    hipLaunchKernelGGL(attn_kernel, dim3(64, 8), dim3(512), 0, stream,
                       Q, wcomb, kb, vT, cnt, wfc16, win16, ln_g, ln_b, out);
}

// Round 13
// 172.377 us; speedup vs baseline: 1.0427x; 1.0107x over previous
//
#include <hip/hip_runtime.h>
#include <hip/hip_bf16.h>
#include <cstdint>

typedef __attribute__((ext_vector_type(8))) short short8;
typedef __attribute__((ext_vector_type(4))) float f32x4;
typedef __attribute__((ext_vector_type(16))) float f32x16;
typedef unsigned short u16;
typedef unsigned int u32;

__device__ __forceinline__ u16 f2bf(float f) {
    union { float f; u32 u; } v; v.f = f;
    u32 u = v.u;
    u = (u + 0x7fffu + ((u >> 16) & 1u)) >> 16;
    return (u16)u;
}

__device__ __forceinline__ float fexp2(float x) {   // v_exp_f32 = 2^x
    float r;
    asm("v_exp_f32 %0, %1" : "=v"(r) : "v"(x));
    return r;
}

__device__ __forceinline__ u32 pk_bf16(float lo, float hi) {
    u32 r;
    asm("v_cvt_pk_bf16_f32 %0, %1, %2" : "=v"(r) : "v"(lo), "v"(hi));
    return r;
}

__device__ __forceinline__ void pl32swap(u32& a, u32& b) {
#if __has_builtin(__builtin_amdgcn_permlane32_swap)
    auto r = __builtin_amdgcn_permlane32_swap((int)a, (int)b, false, false);
    a = (u32)r[0]; b = (u32)r[1];
#else
    u32 ax = (u32)__shfl_xor((int)a, 32), bx = (u32)__shfl_xor((int)b, 32);
    bool hi = (threadIdx.x & 32) != 0;
    u32 na = hi ? bx : a;
    u32 nb = hi ? b : ax;
    a = na; b = nb;
#endif
}

__device__ __forceinline__ void gload_lds16(const u16* g, u16* l) {
    __builtin_amdgcn_global_load_lds((const __attribute__((address_space(1))) void*)g,
                                     (__attribute__((address_space(3))) void*)l, 16, 0, 0);
}

// C-block rows (crow order) -> one 16-k A/B-frag via cvt_pk + permlane32_swap (T12)
__device__ __forceinline__ short8 make_pa(float p0, float p1, float p2, float p3,
                                          float p4, float p5, float p6, float p7) {
    u32 a1 = pk_bf16(p0, p1), b1 = pk_bf16(p4, p5);
    u32 a2 = pk_bf16(p2, p3), b2 = pk_bf16(p6, p7);
    pl32swap(a1, b1); pl32swap(a2, b2);
    union { u32 w[4]; short8 s; } u;
    u.w[0] = a1; u.w[1] = a2; u.w[2] = b1; u.w[3] = b2;
    return u.s;
}

// ---------- kernel 0: weights prep (blocks 0..799) + mask scan (blocks 800..807) ----------
__global__ void prep_kernel(const float* __restrict__ W_in,
                            const float* __restrict__ W_mh,
                            const float* __restrict__ W_fc,
                            const float* __restrict__ qmask,
                            u16* __restrict__ wcomb, u16* __restrict__ wfc16,
                            u16* __restrict__ win16,
                            u16* __restrict__ pos, int* __restrict__ cnt) {
    if (blockIdx.x >= 800) {                     // per-batch stable compaction scan
        if (threadIdx.x >= 64) return;
        int b = blockIdx.x - 800, t = threadIdx.x;
        int base = b * 2048 + t * 32;
        int c = 0;
#pragma unroll
        for (int i = 0; i < 32; ++i) c += (qmask[base + i] != 0.0f) ? 1 : 0;
        int inc = c;
#pragma unroll
        for (int dd = 1; dd < 64; dd <<= 1) {
            int v = __shfl_up(inc, dd);
            if (t >= dd) inc += v;
        }
        int run = inc - c;
#pragma unroll
        for (int i = 0; i < 32; ++i) {
            bool mk = (qmask[base + i] != 0.0f);
            pos[base + i] = mk ? (u16)run : (u16)0xFFFF;
            run += mk ? 1 : 0;
        }
        if (t == 63) cnt[b] = inc;
        return;
    }
    int idx = blockIdx.x * 256 + threadIdx.x;
    if (idx < 1024 * 64) {                       // W_comb = W_mh @ W_in
        int f = idx >> 6, i = idx & 63;
        float acc = 0.f;
        for (int e = 0; e < 128; ++e)
            acc += W_mh[f * 128 + e] * W_in[e * 64 + i];
        wcomb[idx] = f2bf(acc);
    }
    int idx2 = idx - 65536;
    if (idx2 >= 0 && idx2 < 128 * 1024) {
        // wfc16 stored in PERMUTED k-order: k' = sub*128 + l31*4 + dblk
        // (orig k = sub*128 + dblk*32 + l31). Matches attn epilogue's epi layout.
        int e = idx2 >> 10, fp = idx2 & 1023;
        int sub = fp >> 7, r2 = fp & 127;
        int forig = sub * 128 + (r2 & 3) * 32 + (r2 >> 2);
        wfc16[idx2] = f2bf(W_fc[e * 1024 + forig]);
    }
    int idx3 = idx - 65536 - 131072;
    if (idx3 >= 0 && idx3 < 128 * 64)
        win16[idx3] = f2bf(W_in[idx3]);
}

// ---------- kernel 1: k/v projections, compacted rows, LDS-staged 16B stores ----------
__global__ __launch_bounds__(256) void qkv_kernel(
    const float* __restrict__ K, const float* __restrict__ V,
    const u16* __restrict__ wcomb, const u16* __restrict__ pos,
    u16* __restrict__ kb, u16* __restrict__ vrow) {
    __shared__ __align__(16) u16 ot[64 * 264];
    int w = threadIdx.x >> 6, lane = threadIdx.x & 63;
    int g = lane >> 4, c15 = lane & 15;
    const float* X = blockIdx.z == 0 ? K : V;

    int Rrow = blockIdx.x * 64 + w * 16 + c15;
    short8 af[2];
#pragma unroll
    for (int c = 0; c < 2; ++c) {
        const float* p = X + (size_t)Rrow * 64 + 8 * g + 32 * c;
        float4 fa = *(const float4*)(p);
        float4 fb = *(const float4*)(p + 4);
        short8 a;
        a[0] = (short)f2bf(fa.x); a[1] = (short)f2bf(fa.y);
        a[2] = (short)f2bf(fa.z); a[3] = (short)f2bf(fa.w);
        a[4] = (short)f2bf(fb.x); a[5] = (short)f2bf(fb.y);
        a[6] = (short)f2bf(fb.z); a[7] = (short)f2bf(fb.w);
        af[c] = a;
    }
    int colbase = blockIdx.y * 256;
    f32x4 acc[16];
#pragma unroll
    for (int i = 0; i < 16; ++i) acc[i] = {0.f, 0.f, 0.f, 0.f};
#pragma unroll
    for (int cb = 0; cb < 16; ++cb) {
        int col = colbase + cb * 16 + c15;
#pragma unroll
        for (int c = 0; c < 2; ++c) {
            short8 bfr = *(const short8*)(wcomb + (size_t)col * 64 + 8 * g + 32 * c);
            acc[cb] = __builtin_amdgcn_mfma_f32_16x16x32_bf16(af[c], bfr, acc[cb], 0, 0, 0);
        }
    }
    int r0 = w * 16 + 4 * g;
#pragma unroll
    for (int cb = 0; cb < 16; ++cb)
#pragma unroll
        for (int r = 0; r < 4; ++r)
            ot[(r0 + r) * 264 + cb * 16 + c15] = f2bf(acc[cb][r]);
    __syncthreads();
    u16* dstbuf = blockIdx.z == 0 ? kb : vrow;
#pragma unroll
    for (int it = 0; it < 8; ++it) {
        int chunk = threadIdx.x + it * 256;
        int row = chunk >> 5, cc = chunk & 31;
        int R = blockIdx.x * 64 + row;
        u16 p = pos[R];
        if (p != 0xFFFF) {
            int b = R >> 11;
            int col0 = colbase + cc * 8;
            int h = col0 >> 7, d = col0 & 127;
            *(uint4*)(dstbuf + ((size_t)(b * 8 + h) * 2048 + p) * 128 + d) =
                *(const uint4*)(ot + row * 264 + cc * 8);
        }
    }
}

// ---------- kernel 2: transpose compacted V rows -> chunk-major vT[bh][kcg][128][8] ----------
__global__ __launch_bounds__(256) void vtrans_kernel(
    const u16* __restrict__ vrow, const int* __restrict__ cnt,
    u16* __restrict__ vT) {
    int t = blockIdx.x, bh = blockIdx.y, b = bh >> 3;
    int L = cnt[b];
    if (t * 64 >= L) return;
    __shared__ __align__(16) u32 tl[128 * 32];   // [d][32 s-pairs], chunk-XOR swizzled
    const u16* src = vrow + ((size_t)bh * 2048 + t * 64) * 128;
#pragma unroll
    for (int task = 0; task < 2; ++task) {
        int id = threadIdx.x + task * 256;       // 512 tasks: s-pair i x d-chunk c
        int i = id >> 4, c = id & 15;
        int r0 = 2 * i, r1 = 2 * i + 1;
        uint4 A = {0, 0, 0, 0}, Bv = {0, 0, 0, 0};
        if (t * 64 + r0 < L) A  = *(const uint4*)(src + (size_t)r0 * 128 + c * 8);
        if (t * 64 + r1 < L) Bv = *(const uint4*)(src + (size_t)r1 * 128 + c * 8);
        const u32* aw = (const u32*)&A;
        const u32* bw = (const u32*)&Bv;
#pragma unroll
        for (int j = 0; j < 4; ++j) {
            u32 lo  = (aw[j] & 0xFFFFu) | (bw[j] << 16);       // d=8c+2j,  rows (r0,r1)
            u32 hi2 = (aw[j] >> 16) | (bw[j] & 0xFFFF0000u);   // d=8c+2j+1
            int d0 = 8 * c + 2 * j, d1 = d0 + 1;
            int h0 = ((d0 & 7) ^ ((d0 >> 3) & 7)) << 2;
            int h1 = ((d1 & 7) ^ ((d1 >> 3) & 7)) << 2;
            tl[d0 * 32 + (i ^ h0)] = lo;
            tl[d1 * 32 + (i ^ h1)] = hi2;
        }
    }
    __syncthreads();
    int d = threadIdx.x >> 1, half = threadIdx.x & 1;
    int hd = (d & 7) ^ ((d >> 3) & 7);
#pragma unroll
    for (int jc = 0; jc < 4; ++jc) {
        int chunk = (half * 4 + jc) ^ hd;
        int kcg = t * 8 + half * 4 + jc;         // global 8-key chunk index
        *(uint4*)(vT + (((size_t)bh * 256 + kcg) * 128 + d) * 8) =
            *(const uint4*)(&tl[d * 32 + chunk * 4]);
    }
}

// ---------- kernel 3: flash attn (r5 structure) + fused W_fc GEMM + residual + LN ----------
__global__ __launch_bounds__(512, 2) void attn_kernel(
    const float* __restrict__ Qin, const u16* __restrict__ wcomb,
    const u16* __restrict__ kbuf, const u16* __restrict__ vTc,
    const int* __restrict__ cnt,
    const u16* __restrict__ wfc16, const u16* __restrict__ win16,
    const float* __restrict__ ln_g, const float* __restrict__ ln_b,
    float* __restrict__ out) {
    __shared__ __align__(16) u16 smem[32768];    // kt[2][8192] | vt[2][8192]; epi overlay
    __shared__ float2 pls[32][4];                // LN partials: [row][colgroup] (sum, sumsq)

    const int w = threadIdx.x >> 6, lane = threadIdx.x & 63;
    const int hi = lane >> 5, l31 = lane & 31;
    const int g = lane >> 4, c15 = lane & 15;
    const int bh = blockIdx.x, qt = blockIdx.y;  // XCD = bh%8: all qt of a bh share L2
    const int b = bh >> 3, h = bh & 7;
    const int L = cnt[b];
    const int nt = (L + 63) >> 6;

    const u16* kbbh = kbuf + (size_t)bh * 2048 * 128;
    const u16* vTbh = vTc + (size_t)bh * 262144; // 256 kcg * 128 d * 8

    u16* ktb0 = smem;                            // [2][8192]
    u16* vtb0 = smem + 16384;                    // [2][8192] chunk-major: (kcg*128+d)*8

    auto stage = [&](int buf, int tt) {
#pragma unroll
        for (int c = 0; c < 2; ++c) {
            int rl = (c * 8 + w) * 4 + (lane >> 4);     // K: 4 rows per wave-call
            int ck = (lane & 15) ^ (rl & 7);
            gload_lds16(kbbh + ((size_t)(tt * 64 + rl)) * 128 + ck * 8,
                        ktb0 + buf * 8192 + (c * 8 + w) * 512);
            int ci = c * 512 + w * 64 + lane;           // V: pure linear block copy
            gload_lds16(vTbh + ((size_t)tt * 1024 + ci) * 8,
                        vtb0 + buf * 8192 + (c * 512 + w * 64) * 8);
        }
    };

    stage(0, 0);                                 // DMA overlaps q-projection below

    // ---- fused q-projection, scaled by log2(e)/sqrt(128) (softmax in log2 domain) ----
    const float invT2 = 0.12751743f;             // log2(e)/sqrt(128)
    const int q0 = qt * 256 + w * 32;
    const float* qrow = Qin + ((size_t)b * 2048 + q0 + l31) * 64;
    short8 bq[4];
#pragma unroll
    for (int s = 0; s < 4; ++s) {
        const float* p = qrow + s * 16 + hi * 8;
        float4 fa = *(const float4*)(p);
        float4 fb = *(const float4*)(p + 4);
        short8 a;
        a[0] = (short)f2bf(fa.x); a[1] = (short)f2bf(fa.y);
        a[2] = (short)f2bf(fa.z); a[3] = (short)f2bf(fa.w);
        a[4] = (short)f2bf(fb.x); a[5] = (short)f2bf(fb.y);
        a[6] = (short)f2bf(fb.z); a[7] = (short)f2bf(fb.w);
        bq[s] = a;
    }
    short8 qf[8];
#pragma unroll
    for (int dblk = 0; dblk < 4; ++dblk) {
        f32x16 c2;
#pragma unroll
        for (int r = 0; r < 16; ++r) c2[r] = 0.f;
        const u16* wrow = wcomb + (size_t)(h * 128 + dblk * 32 + l31) * 64 + hi * 8;
#pragma unroll
        for (int s = 0; s < 4; ++s) {
            short8 wa = *(const short8*)(wrow + s * 16);
            c2 = __builtin_amdgcn_mfma_f32_32x32x16_bf16(wa, bq[s], c2, 0, 0, 0);
        }
        qf[2 * dblk] = make_pa(c2[0] * invT2, c2[1] * invT2, c2[2] * invT2, c2[3] * invT2,
                               c2[4] * invT2, c2[5] * invT2, c2[6] * invT2, c2[7] * invT2);
        qf[2 * dblk + 1] = make_pa(c2[8] * invT2, c2[9] * invT2, c2[10] * invT2, c2[11] * invT2,
                                   c2[12] * invT2, c2[13] * invT2, c2[14] * invT2, c2[15] * invT2);
    }

    f32x16 o[4];
#pragma unroll
    for (int i = 0; i < 4; ++i)
#pragma unroll
        for (int r = 0; r < 16; ++r) o[i][r] = 0.f;
    float m = -1e30f, lsum = 0.f;

    int cur = 0;
    __syncthreads();

    for (int t = 0; t < nt; ++t) {
        if (t + 1 < nt) stage(cur ^ 1, t + 1);
        const u16* ktb = ktb0 + cur * 8192;
        const u16* vtb = vtb0 + cur * 8192;

        // S^T = K . Q^T (log2 domain)
        f32x16 st0, st1;
#pragma unroll
        for (int r = 0; r < 16; ++r) { st0[r] = 0.f; st1[r] = 0.f; }
        int k0 = l31, k1 = 32 + l31;
#pragma unroll
        for (int ds = 0; ds < 8; ++ds) {
            int sw = ((ds * 2 + hi) ^ (l31 & 7)) << 3;
            short8 kf0 = *(const short8*)(ktb + (k0 << 7) + sw);
            short8 kf1 = *(const short8*)(ktb + (k1 << 7) + sw);
            st0 = __builtin_amdgcn_mfma_f32_32x32x16_bf16(kf0, qf[ds], st0, 0, 0, 0);
            st1 = __builtin_amdgcn_mfma_f32_32x32x16_bf16(kf1, qf[ds], st1, 0, 0, 0);
        }
        if (t == nt - 1) {                      // tail: replace (kills garbage NaN/Inf)
#pragma unroll
            for (int r = 0; r < 16; ++r) {
                int kl = (r & 3) + 8 * (r >> 2) + 4 * hi;
                st0[r] = (t * 64 + kl < L) ? st0[r] : -1e30f;
                st1[r] = (t * 64 + 32 + kl < L) ? st1[r] : -1e30f;
            }
        }
        float mx = st0[0];
#pragma unroll
        for (int r = 1; r < 16; ++r) mx = fmaxf(mx, st0[r]);
#pragma unroll
        for (int r = 0; r < 16; ++r) mx = fmaxf(mx, st1[r]);
        mx = fmaxf(mx, __shfl_xor(mx, 32));
        if (__any(mx - m > 11.0f)) {            // defer-max (log2 units)
            float mn = fmaxf(m, mx);
            float corr = fexp2(m - mn);
            m = mn;
            lsum *= corr;
#pragma unroll
            for (int r = 0; r < 16; ++r) {
                float cc = __shfl(corr, (r & 3) + 8 * (r >> 2) + 4 * hi);
                o[0][r] *= cc; o[1][r] *= cc; o[2][r] *= cc; o[3][r] *= cc;
            }
        }
        float p0a[16], p1a[16];
#pragma unroll
        for (int r = 0; r < 16; ++r) { p0a[r] = fexp2(st0[r] - m); p1a[r] = fexp2(st1[r] - m); }
        float s0 = 0.f, s1 = 0.f, s2 = 0.f, s3 = 0.f;
#pragma unroll
        for (int r = 0; r < 16; r += 4) {
            s0 += p0a[r]; s1 += p0a[r + 1]; s2 += p0a[r + 2]; s3 += p0a[r + 3];
            s0 += p1a[r]; s1 += p1a[r + 1]; s2 += p1a[r + 2]; s3 += p1a[r + 3];
        }
        float tot = (s0 + s1) + (s2 + s3);
        tot += __shfl_xor(tot, 32);
        lsum += tot;
        short8 pa0 = make_pa(p0a[0], p0a[1], p0a[2], p0a[3], p0a[4], p0a[5], p0a[6], p0a[7]);
        short8 pa1 = make_pa(p0a[8], p0a[9], p0a[10], p0a[11], p0a[12], p0a[13], p0a[14], p0a[15]);
        short8 pa2 = make_pa(p1a[0], p1a[1], p1a[2], p1a[3], p1a[4], p1a[5], p1a[6], p1a[7]);
        short8 pa3 = make_pa(p1a[8], p1a[9], p1a[10], p1a[11], p1a[12], p1a[13], p1a[14], p1a[15]);
        // O += P @ V ; V chunk-major (linear, conflict-free)
#pragma unroll
        for (int dblk = 0; dblk < 4; ++dblk) {
#pragma unroll
            for (int ks = 0; ks < 4; ++ks) {
                short8 vf = *(const short8*)(vtb +
                    ((((ks * 2 + hi) << 7) + (dblk << 5) + l31) << 3));
                short8 pa = (ks == 0) ? pa0 : (ks == 1) ? pa1 : (ks == 2) ? pa2 : pa3;
                o[dblk] = __builtin_amdgcn_mfma_f32_32x32x16_bf16(pa, vf, o[dblk], 0, 0, 0);
            }
        }
        __syncthreads();
        cur ^= 1;
    }

    // ---- residual Q@W_in (K=64) FIRST: its global-load latency hides under epi staging ----
    const int rg = w >> 2, cg = w & 3;           // 2 rowgroups x 4 colgroups
    const int srow0 = h * 256 + qt * 32;
    const int row16 = rg * 16 + c15;
    f32x4 acA[2], acB[2];
    acA[0] = {0.f, 0.f, 0.f, 0.f}; acA[1] = {0.f, 0.f, 0.f, 0.f};
    acB[0] = {0.f, 0.f, 0.f, 0.f}; acB[1] = {0.f, 0.f, 0.f, 0.f};
    {
        const float* p0 = Qin + ((size_t)b * 2048 + srow0 + row16) * 64;
        short8 af2[2];
#pragma unroll
        for (int c = 0; c < 2; ++c) {
            float4 fa = *(const float4*)(p0 + 8 * g + 32 * c);
            float4 fb = *(const float4*)(p0 + 8 * g + 32 * c + 4);
            short8 a;
            a[0] = (short)f2bf(fa.x); a[1] = (short)f2bf(fa.y);
            a[2] = (short)f2bf(fa.z); a[3] = (short)f2bf(fa.w);
            a[4] = (short)f2bf(fb.x); a[5] = (short)f2bf(fb.y);
            a[6] = (short)f2bf(fb.z); a[7] = (short)f2bf(fb.w);
            af2[c] = a;
        }
#pragma unroll
        for (int eb = 0; eb < 2; ++eb)
#pragma unroll
            for (int c = 0; c < 2; ++c) {
                short8 bfr = *(const short8*)(win16 +
                    (size_t)(cg * 32 + eb * 16 + c15) * 64 + 8 * g + 32 * c);
                acA[eb] = __builtin_amdgcn_mfma_f32_16x16x32_bf16(af2[c], bfr, acA[eb], 0, 0, 0);
            }
    }

    // ---- fused epilogue: stage 32x1024 attn-out into LDS in PERMUTED k'-order ----
    // k' = (kl&7)*128 + l31*4 + dblk  (wfc16 stores matching permutation).
    // Per lane: 4 contiguous bf16 -> one ds_write_b64. XOR-swizzle 16B chunks by row&7.
    u16* epi = smem;
    float invl = 1.0f / lsum;
#pragma unroll
    for (int r = 0; r < 16; ++r) {
        int kl = (r & 3) + 8 * (r >> 2) + 4 * hi;
        float iv = __shfl(invl, kl);
        int row_local = w * 4 + (kl >> 3);
        u32 w0 = pk_bf16(o[0][r] * iv, o[1][r] * iv);
        u32 w1 = pk_bf16(o[2][r] * iv, o[3][r] * iv);
        int chunk16 = (kl & 7) * 16 + (l31 >> 1);
        int idx = row_local * 1024 + ((chunk16 ^ (row_local & 7)) << 3) + (l31 & 1) * 4;
        *(uint2*)(epi + idx) = make_uint2(w0, w1);
    }
    __syncthreads();

    // ---- W_fc GEMM (K=1024 from epi, permuted k'), parity-split accs ----
    const int rsw = row16 & 7;
#pragma unroll
    for (int kc2 = 0; kc2 < 16; ++kc2) {
        int kcE = 2 * kc2, kcO = 2 * kc2 + 1;
        short8 afE = *(const short8*)(epi + row16 * 1024 + (((kcE * 4 + g) ^ rsw) << 3));
        short8 afO = *(const short8*)(epi + row16 * 1024 + (((kcO * 4 + g) ^ rsw) << 3));
#pragma unroll
        for (int eb = 0; eb < 2; ++eb) {
            short8 bfE = *(const short8*)(wfc16 +
                (size_t)(cg * 32 + eb * 16 + c15) * 1024 + kcE * 32 + 8 * g);
            short8 bfO = *(const short8*)(wfc16 +
                (size_t)(cg * 32 + eb * 16 + c15) * 1024 + kcO * 32 + 8 * g);
            acA[eb] = __builtin_amdgcn_mfma_f32_16x16x32_bf16(afE, bfE, acA[eb], 0, 0, 0);
            acB[eb] = __builtin_amdgcn_mfma_f32_16x16x32_bf16(afO, bfO, acB[eb], 0, 0, 0);
        }
    }
    f32x4 acc2[2];
#pragma unroll
    for (int eb = 0; eb < 2; ++eb)
#pragma unroll
        for (int r = 0; r < 4; ++r)
            acc2[eb][r] = acA[eb][r] + acB[eb][r];
    // ---- LN partials across colgroups (ln_g/ln_b loads hoisted above barrier) ----
    float gg0 = ln_g[cg * 32 + c15],      bb0 = ln_b[cg * 32 + c15];
    float gg1 = ln_g[cg * 32 + 16 + c15], bb1 = ln_b[cg * 32 + 16 + c15];
#pragma unroll
    for (int r = 0; r < 4; ++r) {
        float s = acc2[0][r] + acc2[1][r];
        float q2 = acc2[0][r] * acc2[0][r] + acc2[1][r] * acc2[1][r];
#pragma unroll
        for (int dd = 1; dd < 16; dd <<= 1) {
            s += __shfl_xor(s, dd);
            q2 += __shfl_xor(q2, dd);
        }
        if (c15 == 0) pls[rg * 16 + 4 * g + r][cg] = make_float2(s, q2);
    }
    __syncthreads();
#pragma unroll
    for (int r = 0; r < 4; ++r) {
        int row = rg * 16 + 4 * g + r;
        float2 pa = pls[row][0], pb = pls[row][1], pc = pls[row][2], pd = pls[row][3];
        float mean = (pa.x + pb.x + pc.x + pd.x) * (1.0f / 128.0f);
        float var  = (pa.y + pb.y + pc.y + pd.y) * (1.0f / 128.0f) - mean * mean;
        float rstd = rsqrtf(var + 1e-6f);
        size_t ob = ((size_t)b * 2048 + srow0 + row) * 128;
        out[ob + cg * 32 + c15]      = (acc2[0][r] - mean) * rstd * gg0 + bb0;
        out[ob + cg * 32 + 16 + c15] = (acc2[1][r] - mean) * rstd * gg1 + bb1;
    }
}

// ---------- launcher ----------
extern "C" void kernel_launch(void* const* d_in, const int* in_sizes, int n_in,
                              void* d_out, int out_size, void* d_ws, size_t ws_size,
                              hipStream_t stream) {
    const float* Q     = (const float*)d_in[0];
    const float* K     = (const float*)d_in[1];
    const float* V     = (const float*)d_in[2];
    const float* QMask = (const float*)d_in[3];
    const float* W_in  = (const float*)d_in[4];
    const float* W_mh  = (const float*)d_in[5];
    const float* W_fc  = (const float*)d_in[6];
    const float* ln_g  = (const float*)d_in[7];
    const float* ln_b  = (const float*)d_in[8];
    float* out = (float*)d_out;

    char* ws = (char*)d_ws;
    u16*   wcomb = (u16*)(ws);                   // 131072 B
    u16*   wfc16 = (u16*)(ws + 131072);          // 262144 B (k'-permuted)
    u16*   kb    = (u16*)(ws + 42336256);        // compacted K rows [B*H,S,128]
    u16*   vT    = (u16*)(ws + 75890688);        // chunk-major [B*H][256 kcg][128 d][8]
    u16*   vrow  = (u16*)(ws + 109445120);       // compacted V rows (consumed by vtrans)
    u16*   pos   = (u16*)(ws + 142999552);       // [B,S] compact position or 0xFFFF
    int*   cnt   = (int*)(ws + 143032320);       // [B] unmasked counts
    u16*   win16 = (u16*)(ws + 143036416);       // W_in bf16 [128][64]

    hipLaunchKernelGGL(prep_kernel, dim3(808), dim3(256), 0, stream,
                       W_in, W_mh, W_fc, QMask, wcomb, wfc16, win16, pos, cnt);
    hipLaunchKernelGGL(qkv_kernel, dim3(256, 4, 2), dim3(256), 0, stream,
                       K, V, wcomb, pos, kb, vrow);
    hipLaunchKernelGGL(vtrans_kernel, dim3(32, 64), dim3(256), 0, stream,
                       vrow, cnt, vT);
    hipLaunchKernelGGL(attn_kernel, dim3(64, 8), dim3(512), 0, stream,
                       Q, wcomb, kb, vT, cnt, wfc16, win16, ln_g, ln_b, out);
}